// Round 1
// baseline (1388.544 us; speedup 1.0000x reference)
//
#include <hip/hip_runtime.h>
#include <math.h>

#define N_NODES 100000
#define N_EDGES 3200000
#define B_GRAPHS 500
#define K_TOP 30
#define F_INN 128
#define H1C 64
#define NUM_CLASSES 18
#define XC 65               // H1 + 1
#define P_LEN (K_TOP * XC)  // 1950
#define C3_OUT 16
#define C3_K 97
#define C3_L 20             // (1950-97)/97 + 1
#define P2_L 10
#define C4_OUT 32
#define C4_K 5
#define C4_L 6
#define FC1_IN 192
#define FC1_OUT 128
#define ROWS_PB 16

// ---------------- degree: deg[col] += (row != col) ----------------
__global__ void k_deg(const int* __restrict__ row, const int* __restrict__ col,
                      float* __restrict__ deg) {
    int e = blockIdx.x * blockDim.x + threadIdx.x;
    if (e < N_EDGES) {
        int r = row[e], c = col[e];
        if (r != c) atomicAdd(&deg[c], 1.0f);
    }
}

// ---------------- dis = rsqrt(deg + 1), in place ----------------
__global__ void k_dis(float* __restrict__ d) {
    int n = blockIdx.x * blockDim.x + threadIdx.x;
    if (n < N_NODES) d[n] = rsqrtf(d[n] + 1.0f);
}

// ---------------- coef[e] = dis[row]*dis[col]*w_edge ----------------
__global__ void k_coef(const int* __restrict__ row, const int* __restrict__ col,
                       const float* __restrict__ dis, float* __restrict__ coef) {
    int e = blockIdx.x * blockDim.x + threadIdx.x;
    if (e < N_EDGES) {
        int r = row[e], c = col[e];
        coef[e] = (r != c) ? dis[r] * dis[c] : 0.0f;
    }
}

// ---------------- xw1 = x (N,128) @ W1 (128,64) ----------------
__global__ __launch_bounds__(256) void k_xw1(const float* __restrict__ x,
                                             const float* __restrict__ W1,
                                             float* __restrict__ xw) {
    __shared__ float ws[F_INN * H1C];     // 32 KB
    __shared__ float xs[ROWS_PB * F_INN]; // 8 KB
    int tid = threadIdx.x;
    for (int i = tid; i < F_INN * H1C; i += 256) ws[i] = W1[i];
    int row0 = blockIdx.x * ROWS_PB;
    for (int i = tid; i < ROWS_PB * F_INN; i += 256) {
        int r = row0 + i / F_INN;
        xs[i] = (r < N_NODES) ? x[(size_t)r * F_INN + (i % F_INN)] : 0.0f;
    }
    __syncthreads();
    int c = tid & 63;
    int rb = tid >> 6; // 0..3
    float acc[4] = {0.f, 0.f, 0.f, 0.f};
    for (int k = 0; k < F_INN; ++k) {
        float wv = ws[k * H1C + c];
#pragma unroll
        for (int i = 0; i < 4; ++i)
            acc[i] += xs[(rb + i * 4) * F_INN + k] * wv;
    }
#pragma unroll
    for (int i = 0; i < 4; ++i) {
        int r = row0 + rb + i * 4;
        if (r < N_NODES) xw[(size_t)r * H1C + c] = acc[i];
    }
}

// ---------------- agg1[col] += xw[row] * coef  (wave per edge) ----------------
__global__ __launch_bounds__(256) void k_agg1(const int* __restrict__ row,
                                              const int* __restrict__ col,
                                              const float* __restrict__ coef,
                                              const float* __restrict__ xw,
                                              float* __restrict__ agg) {
    int t = blockIdx.x * 256 + threadIdx.x;
    int e = t >> 6;
    int c = t & 63;
    if (e < N_EDGES) {
        float cf = coef[e];
        if (cf != 0.0f) {
            int r = row[e], cl = col[e];
            atomicAdd(&agg[(size_t)cl * H1C + c], xw[(size_t)r * H1C + c] * cf);
        }
    }
}

// ---------------- x1 = tanh(agg + xw*dis^2 + b1), in place over agg ----------------
__global__ void k_x1(const float* __restrict__ xw, const float* __restrict__ dis,
                     const float* __restrict__ b1, float* __restrict__ agg_x1) {
    int idx = blockIdx.x * 256 + threadIdx.x;
    if (idx < N_NODES * H1C) {
        int n = idx >> 6, c = idx & 63;
        float d = dis[n];
        float v = agg_x1[idx] + xw[idx] * d * d + b1[c];
        agg_x1[idx] = tanhf(v);
    }
}

// ---------------- xw2 = x1 @ W2 (64,1)  (wave per node) ----------------
__global__ void k_xw2(const float* __restrict__ x1, const float* __restrict__ W2,
                      float* __restrict__ xw2) {
    int t = blockIdx.x * 256 + threadIdx.x;
    int n = t >> 6, c = t & 63;
    if (n < N_NODES) {
        float v = x1[(size_t)n * H1C + c] * W2[c];
        for (int off = 32; off; off >>= 1) v += __shfl_down(v, off);
        if (c == 0) xw2[n] = v;
    }
}

// ---------------- agg2[col] += xw2[row]*coef ----------------
__global__ void k_agg2(const int* __restrict__ row, const int* __restrict__ col,
                       const float* __restrict__ coef, const float* __restrict__ xw2,
                       float* __restrict__ agg2) {
    int e = blockIdx.x * blockDim.x + threadIdx.x;
    if (e < N_EDGES) {
        float cf = coef[e];
        if (cf != 0.0f) atomicAdd(&agg2[col[e]], xw2[row[e]] * cf);
    }
}

// ---------------- x2 = tanh(agg2 + xw2*dis^2 + b2); score copy ----------------
__global__ void k_x2(const float* __restrict__ xw2, const float* __restrict__ dis,
                     const float* __restrict__ b2, float* __restrict__ agg2_x2,
                     float* __restrict__ score) {
    int n = blockIdx.x * blockDim.x + threadIdx.x;
    if (n < N_NODES) {
        float d = dis[n];
        float v = tanhf(agg2_x2[n] + xw2[n] * d * d + b2[0]);
        agg2_x2[n] = v;
        score[n] = v;
    }
}

// ---------------- sort-pool: top-30 per graph by (score desc, idx asc) ----------------
__global__ __launch_bounds__(256) void k_pool(const int* __restrict__ batch,
                                              const float* __restrict__ x1,
                                              const float* __restrict__ x2,
                                              float* score, float* __restrict__ p) {
    __shared__ unsigned long long red[256];
    __shared__ int s_start, s_end;
    int g = blockIdx.x;
    int tid = threadIdx.x;
    if (tid == 0) {
        int lo = 0, hi = N_NODES;
        while (lo < hi) { int m = (lo + hi) >> 1; if (batch[m] < g) lo = m + 1; else hi = m; }
        s_start = lo;
        hi = N_NODES;
        while (lo < hi) { int m = (lo + hi) >> 1; if (batch[m] < g + 1) lo = m + 1; else hi = m; }
        s_end = lo;
    }
    __syncthreads();
    int start = s_start, end = s_end;
    int count = end - start;
    int kk = count < K_TOP ? count : K_TOP;
    for (int j = 0; j < kk; ++j) {
        unsigned long long best = 0ULL;
        for (int n = start + tid; n < end; n += 256) {
            float s = score[n];
            unsigned int bits = __float_as_uint(s);
            unsigned int u = (bits & 0x80000000u) ? ~bits : (bits | 0x80000000u);
            unsigned long long key =
                ((unsigned long long)u << 32) | (unsigned int)(~(unsigned int)n);
            if (key > best) best = key;
        }
        red[tid] = best;
        __syncthreads();
        for (int off = 128; off; off >>= 1) {
            if (tid < off) { if (red[tid + off] > red[tid]) red[tid] = red[tid + off]; }
            __syncthreads();
        }
        int node = (int)(~(unsigned int)(red[0] & 0xFFFFFFFFULL));
        if (tid < 64)
            p[(size_t)g * P_LEN + j * XC + tid] = x1[(size_t)node * H1C + tid];
        else if (tid == 64)
            p[(size_t)g * P_LEN + j * XC + 64] = x2[node];
        if (tid == 0) score[node] = -INFINITY;
        __syncthreads();
    }
}

// ---------------- head: conv3 -> relu -> maxpool -> conv4 -> relu -> fc1 -> fc2 -> logsoftmax ----------------
__global__ __launch_bounds__(256) void k_head(const float* __restrict__ p,
                                              const float* __restrict__ w3, const float* __restrict__ b3,
                                              const float* __restrict__ w4, const float* __restrict__ b4,
                                              const float* __restrict__ fw1, const float* __restrict__ fb1,
                                              const float* __restrict__ fw2, const float* __restrict__ fb2,
                                              float* __restrict__ out) {
    __shared__ float ps[P_LEN];
    __shared__ float h1s[C3_OUT * C3_L];
    __shared__ float h2s[C3_OUT * P2_L];
    __shared__ float h3s[FC1_IN];
    __shared__ float lls[FC1_OUT];
    __shared__ float outs[NUM_CLASSES];
    int g = blockIdx.x, tid = threadIdx.x;
    for (int i = tid; i < P_LEN; i += 256) ps[i] = p[(size_t)g * P_LEN + i];
    __syncthreads();
    for (int o = tid; o < C3_OUT * C3_L; o += 256) {
        int oc = o / C3_L, pos = o % C3_L;
        float s = b3[oc];
        const float* w = w3 + oc * C3_K;
        int base = pos * C3_K;
        for (int k = 0; k < C3_K; ++k) s += ps[base + k] * w[k];
        h1s[o] = fmaxf(s, 0.0f);
    }
    __syncthreads();
    if (tid < C3_OUT * P2_L) {
        int oc = tid / P2_L, pos = tid % P2_L;
        h2s[tid] = fmaxf(h1s[oc * C3_L + 2 * pos], h1s[oc * C3_L + 2 * pos + 1]);
    }
    __syncthreads();
    if (tid < C4_OUT * C4_L) {
        int oc = tid / C4_L, pos = tid % C4_L;
        float s = b4[oc];
        for (int ic = 0; ic < C3_OUT; ++ic)
#pragma unroll
            for (int k = 0; k < C4_K; ++k)
                s += h2s[ic * P2_L + pos + k] * w4[oc * C3_OUT * C4_K + ic * C4_K + k];
        h3s[oc * C4_L + pos] = fmaxf(s, 0.0f);
    }
    __syncthreads();
    if (tid < FC1_OUT) {
        float s = fb1[tid];
        for (int i = 0; i < FC1_IN; ++i) s += h3s[i] * fw1[i * FC1_OUT + tid];
        float v = fmaxf(s, 0.0f);
        lls[tid] = v;
        out[2 * B_GRAPHS * NUM_CLASSES + (size_t)g * FC1_OUT + tid] = v;
    }
    __syncthreads();
    if (tid < NUM_CLASSES) {
        float s = fb2[tid];
        for (int j = 0; j < FC1_OUT; ++j) s += lls[j] * fw2[j * NUM_CLASSES + tid];
        outs[tid] = s;
        out[B_GRAPHS * NUM_CLASSES + (size_t)g * NUM_CLASSES + tid] = s;
    }
    __syncthreads();
    if (tid < NUM_CLASSES) {
        float m = -INFINITY;
        for (int k2 = 0; k2 < NUM_CLASSES; ++k2) m = fmaxf(m, outs[k2]);
        float se = 0.0f;
        for (int k2 = 0; k2 < NUM_CLASSES; ++k2) se += expf(outs[k2] - m);
        out[(size_t)g * NUM_CLASSES + tid] = outs[tid] - m - logf(se);
    }
}

extern "C" void kernel_launch(void* const* d_in, const int* in_sizes, int n_in,
                              void* d_out, int out_size, void* d_ws, size_t ws_size,
                              hipStream_t stream) {
    const float* x   = (const float*)d_in[0];
    const int*   ei  = (const int*)d_in[1];
    const int*   row = ei;
    const int*   col = ei + N_EDGES;
    const int*   bat = (const int*)d_in[2];
    const float* W1  = (const float*)d_in[4];
    const float* b1  = (const float*)d_in[5];
    const float* W2  = (const float*)d_in[6];
    const float* b2  = (const float*)d_in[7];
    const float* w3  = (const float*)d_in[8];
    const float* b3  = (const float*)d_in[9];
    const float* w4  = (const float*)d_in[10];
    const float* b4  = (const float*)d_in[11];
    const float* fw1 = (const float*)d_in[12];
    const float* fb1 = (const float*)d_in[13];
    const float* fw2 = (const float*)d_in[14];
    const float* fb2 = (const float*)d_in[15];

    float* ws    = (float*)d_ws;
    float* xw1   = ws;                                  // N*64
    float* x1    = xw1 + (size_t)N_NODES * H1C;         // N*64 (agg1 then x1)
    float* coef  = x1 + (size_t)N_NODES * H1C;          // E
    float* dis   = coef + (size_t)N_EDGES;              // N (deg then dis)
    float* xw2   = dis + N_NODES;                       // N
    float* x2    = xw2 + N_NODES;                       // N (agg2 then x2)
    float* score = x2 + N_NODES;                        // N
    float* p     = score + N_NODES;                     // B*1950
    float* outp  = (float*)d_out;

    hipMemsetAsync(x1, 0, (size_t)N_NODES * H1C * sizeof(float), stream);
    hipMemsetAsync(dis, 0, (size_t)N_NODES * sizeof(float), stream);
    hipMemsetAsync(x2, 0, (size_t)N_NODES * sizeof(float), stream);
    hipMemsetAsync(p, 0, (size_t)B_GRAPHS * P_LEN * sizeof(float), stream);

    k_deg<<<(N_EDGES + 255) / 256, 256, 0, stream>>>(row, col, dis);
    k_dis<<<(N_NODES + 255) / 256, 256, 0, stream>>>(dis);
    k_coef<<<(N_EDGES + 255) / 256, 256, 0, stream>>>(row, col, dis, coef);
    k_xw1<<<(N_NODES + ROWS_PB - 1) / ROWS_PB, 256, 0, stream>>>(x, W1, xw1);
    k_agg1<<<N_EDGES / 4, 256, 0, stream>>>(row, col, coef, xw1, x1);
    k_x1<<<(N_NODES * H1C + 255) / 256, 256, 0, stream>>>(xw1, dis, b1, x1);
    k_xw2<<<(N_NODES * H1C + 255) / 256, 256, 0, stream>>>(x1, W2, xw2);
    k_agg2<<<(N_EDGES + 255) / 256, 256, 0, stream>>>(row, col, coef, xw2, x2);
    k_x2<<<(N_NODES + 255) / 256, 256, 0, stream>>>(xw2, dis, b2, x2, score);
    k_pool<<<B_GRAPHS, 256, 0, stream>>>(bat, x1, x2, score, p);
    k_head<<<B_GRAPHS, 256, 0, stream>>>(p, w3, b3, w4, b4, fw1, fb1, fw2, fb2, outp);
}

// Round 2
// 974.166 us; speedup vs baseline: 1.4254x; 1.4254x over previous
//
#include <hip/hip_runtime.h>
#include <math.h>

#define N_NODES 100000
#define N_EDGES 3200000
#define B_GRAPHS 500
#define K_TOP 30
#define F_INN 128
#define H1C 64
#define NUM_CLASSES 18
#define XC 65               // H1 + 1
#define P_LEN (K_TOP * XC)  // 1950
#define C3_OUT 16
#define C3_K 97
#define C3_L 20
#define P2_L 10
#define C4_OUT 32
#define C4_K 5
#define C4_L 6
#define FC1_IN 192
#define FC1_OUT 128
#define ROWS_PB 16

// ---------------- histogram of destination degree (non-self edges) ----------------
__global__ void k_hist(const int* __restrict__ row, const int* __restrict__ col,
                       int* __restrict__ cnt) {
    int e = blockIdx.x * blockDim.x + threadIdx.x;
    if (e < N_EDGES) {
        int r = row[e], c = col[e];
        if (r != c) atomicAdd(&cnt[c], 1);
    }
}

// ---------------- dis = rsqrt(deg + 1) ----------------
__global__ void k_dis(const int* __restrict__ cnt, float* __restrict__ dis) {
    int n = blockIdx.x * blockDim.x + threadIdx.x;
    if (n < N_NODES) dis[n] = rsqrtf((float)cnt[n] + 1.0f);
}

// ---------------- exclusive scan of cnt -> rowptr (N+1), copy to wptr ----------------
__global__ __launch_bounds__(1024) void k_scan(const int* __restrict__ cnt,
                                               int* __restrict__ rowptr,
                                               int* __restrict__ wptr) {
    __shared__ int s[1024];
    int t = threadIdx.x;
    const int CH = (N_NODES + 1023) / 1024; // 98
    int lo = t * CH;
    int hi = lo + CH; if (hi > N_NODES) hi = N_NODES;
    if (lo > N_NODES) lo = N_NODES;
    int sum = 0;
    for (int i = lo; i < hi; ++i) sum += cnt[i];
    s[t] = sum;
    __syncthreads();
    for (int off = 1; off < 1024; off <<= 1) {
        int v = (t >= off) ? s[t - off] : 0;
        __syncthreads();
        s[t] += v;
        __syncthreads();
    }
    int pre = (t == 0) ? 0 : s[t - 1];
    for (int i = lo; i < hi; ++i) { rowptr[i] = pre; wptr[i] = pre; pre += cnt[i]; }
    if (t == 1023) rowptr[N_NODES] = pre;
}

// ---------------- scatter edges into CSR-by-col: edata[pos] = {row, coef} ----------------
__global__ void k_scatter(const int* __restrict__ row, const int* __restrict__ col,
                          const float* __restrict__ dis, int* __restrict__ wptr,
                          int2* __restrict__ edata) {
    int e = blockIdx.x * blockDim.x + threadIdx.x;
    if (e < N_EDGES) {
        int r = row[e], c = col[e];
        if (r != c) {
            int pos = atomicAdd(&wptr[c], 1);
            float cf = dis[r] * dis[c];
            edata[pos] = make_int2(r, __float_as_int(cf));
        }
    }
}

// ---------------- xw1 = x (N,128) @ W1 (128,64) ----------------
__global__ __launch_bounds__(256) void k_xw1(const float* __restrict__ x,
                                             const float* __restrict__ W1,
                                             float* __restrict__ xw) {
    __shared__ float ws[F_INN * H1C];     // 32 KB
    __shared__ float xs[ROWS_PB * F_INN]; // 8 KB
    int tid = threadIdx.x;
    for (int i = tid; i < F_INN * H1C; i += 256) ws[i] = W1[i];
    int row0 = blockIdx.x * ROWS_PB;
    for (int i = tid; i < ROWS_PB * F_INN; i += 256) {
        int r = row0 + i / F_INN;
        xs[i] = (r < N_NODES) ? x[(size_t)r * F_INN + (i % F_INN)] : 0.0f;
    }
    __syncthreads();
    int c = tid & 63;
    int rb = tid >> 6;
    float acc[4] = {0.f, 0.f, 0.f, 0.f};
    for (int k = 0; k < F_INN; ++k) {
        float wv = ws[k * H1C + c];
#pragma unroll
        for (int i = 0; i < 4; ++i)
            acc[i] += xs[(rb + i * 4) * F_INN + k] * wv;
    }
#pragma unroll
    for (int i = 0; i < 4; ++i) {
        int r = row0 + rb + i * 4;
        if (r < N_NODES) xw[(size_t)r * H1C + c] = acc[i];
    }
}

// ------- conv1 gather-aggregate + tanh epilogue + xw2 reduce (wave per node) -------
__global__ __launch_bounds__(256) void k_agg1f(const int* __restrict__ rowptr,
                                               const int2* __restrict__ edata,
                                               const float* __restrict__ xw,
                                               const float* __restrict__ dis,
                                               const float* __restrict__ b1,
                                               const float* __restrict__ W2,
                                               float* __restrict__ x1,
                                               float* __restrict__ xw2) {
    int wid = blockIdx.x * 4 + (threadIdx.x >> 6);
    int lane = threadIdx.x & 63;
    if (wid >= N_NODES) return;
    int base = rowptr[wid], endp = rowptr[wid + 1];
    float acc = 0.0f;
    for (int e0 = base; e0 < endp; e0 += 64) {
        int idx = e0 + lane;
        int2 ed = (idx < endp) ? edata[idx] : make_int2(0, 0);
        int m = endp - e0; if (m > 64) m = 64;
        for (int j = 0; j < m; ++j) {
            int r = __shfl(ed.x, j);
            float cf = __int_as_float(__shfl(ed.y, j));
            acc += xw[(size_t)r * H1C + lane] * cf;
        }
    }
    float d = dis[wid];
    float v = tanhf(acc + xw[(size_t)wid * H1C + lane] * d * d + b1[lane]);
    x1[(size_t)wid * H1C + lane] = v;
    float s = v * W2[lane];
    for (int off = 32; off; off >>= 1) s += __shfl_xor(s, off);
    if (lane == 0) xw2[wid] = s;
}

// ------- conv2 gather-aggregate (scalar) + tanh + score (wave per node) -------
__global__ __launch_bounds__(256) void k_agg2f(const int* __restrict__ rowptr,
                                               const int2* __restrict__ edata,
                                               const float* __restrict__ xw2,
                                               const float* __restrict__ dis,
                                               const float* __restrict__ b2,
                                               float* __restrict__ x2,
                                               float* __restrict__ score) {
    int wid = blockIdx.x * 4 + (threadIdx.x >> 6);
    int lane = threadIdx.x & 63;
    if (wid >= N_NODES) return;
    int base = rowptr[wid], endp = rowptr[wid + 1];
    float acc = 0.0f;
    for (int idx = base + lane; idx < endp; idx += 64) {
        int2 ed = edata[idx];
        acc += xw2[ed.x] * __int_as_float(ed.y);
    }
    for (int off = 32; off; off >>= 1) acc += __shfl_xor(acc, off);
    if (lane == 0) {
        float d = dis[wid];
        float v = tanhf(acc + xw2[wid] * d * d + b2[0]);
        x2[wid] = v;
        score[wid] = v;
    }
}

// ---------------- sort-pool: top-30 per graph by (score desc, idx asc) ----------------
__global__ __launch_bounds__(256) void k_pool(const int* __restrict__ batch,
                                              const float* __restrict__ x1,
                                              const float* __restrict__ x2,
                                              float* score, float* __restrict__ p) {
    __shared__ unsigned long long red[256];
    __shared__ int s_start, s_end;
    int g = blockIdx.x;
    int tid = threadIdx.x;
    if (tid == 0) {
        int lo = 0, hi = N_NODES;
        while (lo < hi) { int m = (lo + hi) >> 1; if (batch[m] < g) lo = m + 1; else hi = m; }
        s_start = lo;
        hi = N_NODES;
        while (lo < hi) { int m = (lo + hi) >> 1; if (batch[m] < g + 1) lo = m + 1; else hi = m; }
        s_end = lo;
    }
    __syncthreads();
    int start = s_start, end = s_end;
    int count = end - start;
    int kk = count < K_TOP ? count : K_TOP;
    for (int j = 0; j < kk; ++j) {
        unsigned long long best = 0ULL;
        for (int n = start + tid; n < end; n += 256) {
            float s = score[n];
            unsigned int bits = __float_as_uint(s);
            unsigned int u = (bits & 0x80000000u) ? ~bits : (bits | 0x80000000u);
            unsigned long long key =
                ((unsigned long long)u << 32) | (unsigned int)(~(unsigned int)n);
            if (key > best) best = key;
        }
        red[tid] = best;
        __syncthreads();
        for (int off = 128; off; off >>= 1) {
            if (tid < off) { if (red[tid + off] > red[tid]) red[tid] = red[tid + off]; }
            __syncthreads();
        }
        int node = (int)(~(unsigned int)(red[0] & 0xFFFFFFFFULL));
        if (tid < 64)
            p[(size_t)g * P_LEN + j * XC + tid] = x1[(size_t)node * H1C + tid];
        else if (tid == 64)
            p[(size_t)g * P_LEN + j * XC + 64] = x2[node];
        if (tid == 0) score[node] = -INFINITY;
        __syncthreads();
    }
}

// ---------------- head ----------------
__global__ __launch_bounds__(256) void k_head(const float* __restrict__ p,
                                              const float* __restrict__ w3, const float* __restrict__ b3,
                                              const float* __restrict__ w4, const float* __restrict__ b4,
                                              const float* __restrict__ fw1, const float* __restrict__ fb1,
                                              const float* __restrict__ fw2, const float* __restrict__ fb2,
                                              float* __restrict__ out) {
    __shared__ float ps[P_LEN];
    __shared__ float h1s[C3_OUT * C3_L];
    __shared__ float h2s[C3_OUT * P2_L];
    __shared__ float h3s[FC1_IN];
    __shared__ float lls[FC1_OUT];
    __shared__ float outs[NUM_CLASSES];
    int g = blockIdx.x, tid = threadIdx.x;
    for (int i = tid; i < P_LEN; i += 256) ps[i] = p[(size_t)g * P_LEN + i];
    __syncthreads();
    for (int o = tid; o < C3_OUT * C3_L; o += 256) {
        int oc = o / C3_L, pos = o % C3_L;
        float s = b3[oc];
        const float* w = w3 + oc * C3_K;
        int base = pos * C3_K;
        for (int k = 0; k < C3_K; ++k) s += ps[base + k] * w[k];
        h1s[o] = fmaxf(s, 0.0f);
    }
    __syncthreads();
    if (tid < C3_OUT * P2_L) {
        int oc = tid / P2_L, pos = tid % P2_L;
        h2s[tid] = fmaxf(h1s[oc * C3_L + 2 * pos], h1s[oc * C3_L + 2 * pos + 1]);
    }
    __syncthreads();
    if (tid < C4_OUT * C4_L) {
        int oc = tid / C4_L, pos = tid % C4_L;
        float s = b4[oc];
        for (int ic = 0; ic < C3_OUT; ++ic)
#pragma unroll
            for (int k = 0; k < C4_K; ++k)
                s += h2s[ic * P2_L + pos + k] * w4[oc * C3_OUT * C4_K + ic * C4_K + k];
        h3s[oc * C4_L + pos] = fmaxf(s, 0.0f);
    }
    __syncthreads();
    if (tid < FC1_OUT) {
        float s = fb1[tid];
        for (int i = 0; i < FC1_IN; ++i) s += h3s[i] * fw1[i * FC1_OUT + tid];
        float v = fmaxf(s, 0.0f);
        lls[tid] = v;
        out[2 * B_GRAPHS * NUM_CLASSES + (size_t)g * FC1_OUT + tid] = v;
    }
    __syncthreads();
    if (tid < NUM_CLASSES) {
        float s = fb2[tid];
        for (int j = 0; j < FC1_OUT; ++j) s += lls[j] * fw2[j * NUM_CLASSES + tid];
        outs[tid] = s;
        out[B_GRAPHS * NUM_CLASSES + (size_t)g * NUM_CLASSES + tid] = s;
    }
    __syncthreads();
    if (tid < NUM_CLASSES) {
        float m = -INFINITY;
        for (int k2 = 0; k2 < NUM_CLASSES; ++k2) m = fmaxf(m, outs[k2]);
        float se = 0.0f;
        for (int k2 = 0; k2 < NUM_CLASSES; ++k2) se += expf(outs[k2] - m);
        out[(size_t)g * NUM_CLASSES + tid] = outs[tid] - m - logf(se);
    }
}

extern "C" void kernel_launch(void* const* d_in, const int* in_sizes, int n_in,
                              void* d_out, int out_size, void* d_ws, size_t ws_size,
                              hipStream_t stream) {
    const float* x   = (const float*)d_in[0];
    const int*   ei  = (const int*)d_in[1];
    const int*   row = ei;
    const int*   col = ei + N_EDGES;
    const int*   bat = (const int*)d_in[2];
    const float* W1  = (const float*)d_in[4];
    const float* b1  = (const float*)d_in[5];
    const float* W2  = (const float*)d_in[6];
    const float* b2  = (const float*)d_in[7];
    const float* w3  = (const float*)d_in[8];
    const float* b3  = (const float*)d_in[9];
    const float* w4  = (const float*)d_in[10];
    const float* b4  = (const float*)d_in[11];
    const float* fw1 = (const float*)d_in[12];
    const float* fb1 = (const float*)d_in[13];
    const float* fw2 = (const float*)d_in[14];
    const float* fb2 = (const float*)d_in[15];

    char* wsb = (char*)d_ws;
    float* xw1    = (float*)wsb;                      wsb += (size_t)N_NODES * H1C * 4;  // 25.6 MB
    float* x1     = (float*)wsb;                      wsb += (size_t)N_NODES * H1C * 4;  // 25.6 MB
    int2*  edata  = (int2*)wsb;                       wsb += (size_t)N_EDGES * 8;        // 25.6 MB
    int*   cnt    = (int*)wsb;                        wsb += (size_t)N_NODES * 4;
    int*   rowptr = (int*)wsb;                        wsb += (size_t)(N_NODES + 1) * 4;
    int*   wptr   = (int*)wsb;                        wsb += (size_t)N_NODES * 4;
    float* dis    = (float*)wsb;                      wsb += (size_t)N_NODES * 4;
    float* xw2    = (float*)wsb;                      wsb += (size_t)N_NODES * 4;
    float* x2     = (float*)wsb;                      wsb += (size_t)N_NODES * 4;
    float* score  = (float*)wsb;                      wsb += (size_t)N_NODES * 4;
    float* p      = (float*)wsb;                      wsb += (size_t)B_GRAPHS * P_LEN * 4;
    float* outp   = (float*)d_out;

    hipMemsetAsync(cnt, 0, (size_t)N_NODES * 4, stream);
    hipMemsetAsync(p, 0, (size_t)B_GRAPHS * P_LEN * 4, stream);

    k_hist<<<(N_EDGES + 255) / 256, 256, 0, stream>>>(row, col, cnt);
    k_dis<<<(N_NODES + 255) / 256, 256, 0, stream>>>(cnt, dis);
    k_scan<<<1, 1024, 0, stream>>>(cnt, rowptr, wptr);
    k_scatter<<<(N_EDGES + 255) / 256, 256, 0, stream>>>(row, col, dis, wptr, edata);
    k_xw1<<<(N_NODES + ROWS_PB - 1) / ROWS_PB, 256, 0, stream>>>(x, W1, xw1);
    k_agg1f<<<(N_NODES + 3) / 4, 256, 0, stream>>>(rowptr, edata, xw1, dis, b1, W2, x1, xw2);
    k_agg2f<<<(N_NODES + 3) / 4, 256, 0, stream>>>(rowptr, edata, xw2, dis, b2, x2, score);
    k_pool<<<B_GRAPHS, 256, 0, stream>>>(bat, x1, x2, score, p);
    k_head<<<B_GRAPHS, 256, 0, stream>>>(p, w3, b3, w4, b4, fw1, fb1, fw2, fb2, outp);
}

// Round 3
// 760.124 us; speedup vs baseline: 1.8267x; 1.2816x over previous
//
#include <hip/hip_runtime.h>
#include <math.h>

#define N_NODES 100000
#define N_EDGES 3200000
#define B_GRAPHS 500
#define K_TOP 30
#define F_INN 128
#define H1C 64
#define NUM_CLASSES 18
#define XC 65               // H1 + 1
#define P_LEN (K_TOP * XC)  // 1950
#define C3_OUT 16
#define C3_K 97
#define C3_L 20
#define P2_L 10
#define C4_OUT 32
#define C4_K 5
#define C4_L 6
#define FC1_IN 192
#define FC1_OUT 128
#define ROWS_PB 16
#define NSB ((N_NODES + 255) / 256)   // 391 scan blocks

// ---------------- histogram of destination degree (non-self edges) ----------------
__global__ void k_hist(const int* __restrict__ row, const int* __restrict__ col,
                       int* __restrict__ cnt) {
    int e = blockIdx.x * blockDim.x + threadIdx.x;
    if (e < N_EDGES) {
        int r = row[e], c = col[e];
        if (r != c) atomicAdd(&cnt[c], 1);
    }
}

// ---------------- dis = rsqrt(deg + 1) ----------------
__global__ void k_dis(const int* __restrict__ cnt, float* __restrict__ dis) {
    int n = blockIdx.x * blockDim.x + threadIdx.x;
    if (n < N_NODES) dis[n] = rsqrtf((float)cnt[n] + 1.0f);
}

// ---------------- scan stage 1: per-block sums ----------------
__global__ __launch_bounds__(256) void k_bsum(const int* __restrict__ cnt,
                                              int* __restrict__ bsum) {
    __shared__ int s[256];
    int b = blockIdx.x, t = threadIdx.x;
    int i = b * 256 + t;
    s[t] = (i < N_NODES) ? cnt[i] : 0;
    __syncthreads();
    for (int off = 128; off; off >>= 1) {
        if (t < off) s[t] += s[t + off];
        __syncthreads();
    }
    if (t == 0) bsum[b] = s[0];
}

// ---------------- scan stage 2: exclusive scan of 391 block sums ----------------
__global__ __launch_bounds__(512) void k_scanb(int* __restrict__ bsum) {
    __shared__ int s[512];
    int t = threadIdx.x;
    int v = (t < NSB) ? bsum[t] : 0;
    s[t] = v;
    __syncthreads();
    for (int off = 1; off < 512; off <<= 1) {
        int add = (t >= off) ? s[t - off] : 0;
        __syncthreads();
        s[t] += add;
        __syncthreads();
    }
    if (t < NSB) bsum[t] = s[t] - v;
}

// ---------------- scan stage 3: in-block scan + offset -> rowptr, wptr ----------------
__global__ __launch_bounds__(256) void k_rowptr(const int* __restrict__ cnt,
                                                const int* __restrict__ bsum,
                                                int* __restrict__ rowptr,
                                                int* __restrict__ wptr) {
    __shared__ int s[256];
    int b = blockIdx.x, t = threadIdx.x;
    int i = b * 256 + t;
    int v = (i < N_NODES) ? cnt[i] : 0;
    s[t] = v;
    __syncthreads();
    for (int off = 1; off < 256; off <<= 1) {
        int add = (t >= off) ? s[t - off] : 0;
        __syncthreads();
        s[t] += add;
        __syncthreads();
    }
    int ex = s[t] - v;
    int base = bsum[b];
    if (i < N_NODES) {
        rowptr[i] = base + ex;
        wptr[i] = base + ex;
        if (i == N_NODES - 1) rowptr[N_NODES] = base + ex + v;
    }
}

// ---------------- scatter edges into CSR-by-col: edata[pos] = {row, coef} ----------------
__global__ void k_scatter(const int* __restrict__ row, const int* __restrict__ col,
                          const float* __restrict__ dis, int* __restrict__ wptr,
                          int2* __restrict__ edata) {
    int e = blockIdx.x * blockDim.x + threadIdx.x;
    if (e < N_EDGES) {
        int r = row[e], c = col[e];
        if (r != c) {
            int pos = atomicAdd(&wptr[c], 1);
            float cf = dis[r] * dis[c];
            edata[pos] = make_int2(r, __float_as_int(cf));
        }
    }
}

// ---------------- xw1 = x (N,128) @ W1 (128,64) ----------------
__global__ __launch_bounds__(256) void k_xw1(const float* __restrict__ x,
                                             const float* __restrict__ W1,
                                             float* __restrict__ xw) {
    __shared__ float ws[F_INN * H1C];     // 32 KB
    __shared__ float xs[ROWS_PB * F_INN]; // 8 KB
    int tid = threadIdx.x;
    for (int i = tid; i < F_INN * H1C; i += 256) ws[i] = W1[i];
    int row0 = blockIdx.x * ROWS_PB;
    for (int i = tid; i < ROWS_PB * F_INN; i += 256) {
        int r = row0 + i / F_INN;
        xs[i] = (r < N_NODES) ? x[(size_t)r * F_INN + (i % F_INN)] : 0.0f;
    }
    __syncthreads();
    int c = tid & 63;
    int rb = tid >> 6;
    float acc[4] = {0.f, 0.f, 0.f, 0.f};
    for (int k = 0; k < F_INN; ++k) {
        float wv = ws[k * H1C + c];
#pragma unroll
        for (int i = 0; i < 4; ++i)
            acc[i] += xs[(rb + i * 4) * F_INN + k] * wv;
    }
#pragma unroll
    for (int i = 0; i < 4; ++i) {
        int r = row0 + rb + i * 4;
        if (r < N_NODES) xw[(size_t)r * H1C + c] = acc[i];
    }
}

// ------- conv1 gather-aggregate + tanh epilogue + xw2 reduce (wave per node) -------
__global__ __launch_bounds__(256) void k_agg1f(const int* __restrict__ rowptr,
                                               const int2* __restrict__ edata,
                                               const float* __restrict__ xw,
                                               const float* __restrict__ dis,
                                               const float* __restrict__ b1,
                                               const float* __restrict__ W2,
                                               float* __restrict__ x1,
                                               float* __restrict__ xw2) {
    int wid = blockIdx.x * 4 + (threadIdx.x >> 6);
    int lane = threadIdx.x & 63;
    if (wid >= N_NODES) return;
    int base = rowptr[wid], endp = rowptr[wid + 1];
    float acc = 0.0f;
    for (int e0 = base; e0 < endp; e0 += 64) {
        int idx = e0 + lane;
        int2 ed = (idx < endp) ? edata[idx] : make_int2(0, 0);
        int m = endp - e0; if (m > 64) m = 64;
        for (int j = 0; j < m; ++j) {
            int r = __shfl(ed.x, j);
            float cf = __int_as_float(__shfl(ed.y, j));
            acc += xw[(size_t)r * H1C + lane] * cf;
        }
    }
    float d = dis[wid];
    float v = tanhf(acc + xw[(size_t)wid * H1C + lane] * d * d + b1[lane]);
    x1[(size_t)wid * H1C + lane] = v;
    float s = v * W2[lane];
    for (int off = 32; off; off >>= 1) s += __shfl_xor(s, off);
    if (lane == 0) xw2[wid] = s;
}

// ------- conv2 gather-aggregate (scalar) + tanh + score (wave per node) -------
__global__ __launch_bounds__(256) void k_agg2f(const int* __restrict__ rowptr,
                                               const int2* __restrict__ edata,
                                               const float* __restrict__ xw2,
                                               const float* __restrict__ dis,
                                               const float* __restrict__ b2,
                                               float* __restrict__ x2,
                                               float* __restrict__ score) {
    int wid = blockIdx.x * 4 + (threadIdx.x >> 6);
    int lane = threadIdx.x & 63;
    if (wid >= N_NODES) return;
    int base = rowptr[wid], endp = rowptr[wid + 1];
    float acc = 0.0f;
    for (int idx = base + lane; idx < endp; idx += 64) {
        int2 ed = edata[idx];
        acc += xw2[ed.x] * __int_as_float(ed.y);
    }
    for (int off = 32; off; off >>= 1) acc += __shfl_xor(acc, off);
    if (lane == 0) {
        float d = dis[wid];
        float v = tanhf(acc + xw2[wid] * d * d + b2[0]);
        x2[wid] = v;
        score[wid] = v;
    }
}

// ---------------- sort-pool: top-30 per graph by (score desc, idx asc) ----------------
__global__ __launch_bounds__(256) void k_pool(const int* __restrict__ batch,
                                              const float* __restrict__ x1,
                                              const float* __restrict__ x2,
                                              float* score, float* __restrict__ p) {
    __shared__ unsigned long long red[256];
    __shared__ int s_start, s_end;
    int g = blockIdx.x;
    int tid = threadIdx.x;
    if (tid == 0) {
        int lo = 0, hi = N_NODES;
        while (lo < hi) { int m = (lo + hi) >> 1; if (batch[m] < g) lo = m + 1; else hi = m; }
        s_start = lo;
        hi = N_NODES;
        while (lo < hi) { int m = (lo + hi) >> 1; if (batch[m] < g + 1) lo = m + 1; else hi = m; }
        s_end = lo;
    }
    __syncthreads();
    int start = s_start, end = s_end;
    int count = end - start;
    int kk = count < K_TOP ? count : K_TOP;
    for (int j = 0; j < kk; ++j) {
        unsigned long long best = 0ULL;
        for (int n = start + tid; n < end; n += 256) {
            float s = score[n];
            unsigned int bits = __float_as_uint(s);
            unsigned int u = (bits & 0x80000000u) ? ~bits : (bits | 0x80000000u);
            unsigned long long key =
                ((unsigned long long)u << 32) | (unsigned int)(~(unsigned int)n);
            if (key > best) best = key;
        }
        red[tid] = best;
        __syncthreads();
        for (int off = 128; off; off >>= 1) {
            if (tid < off) { if (red[tid + off] > red[tid]) red[tid] = red[tid + off]; }
            __syncthreads();
        }
        int node = (int)(~(unsigned int)(red[0] & 0xFFFFFFFFULL));
        if (tid < 64)
            p[(size_t)g * P_LEN + j * XC + tid] = x1[(size_t)node * H1C + tid];
        else if (tid == 64)
            p[(size_t)g * P_LEN + j * XC + 64] = x2[node];
        if (tid == 0) score[node] = -INFINITY;
        __syncthreads();
    }
}

// ---------------- head ----------------
__global__ __launch_bounds__(256) void k_head(const float* __restrict__ p,
                                              const float* __restrict__ w3, const float* __restrict__ b3,
                                              const float* __restrict__ w4, const float* __restrict__ b4,
                                              const float* __restrict__ fw1, const float* __restrict__ fb1,
                                              const float* __restrict__ fw2, const float* __restrict__ fb2,
                                              float* __restrict__ out) {
    __shared__ float ps[P_LEN];
    __shared__ float h1s[C3_OUT * C3_L];
    __shared__ float h2s[C3_OUT * P2_L];
    __shared__ float h3s[FC1_IN];
    __shared__ float lls[FC1_OUT];
    __shared__ float outs[NUM_CLASSES];
    int g = blockIdx.x, tid = threadIdx.x;
    for (int i = tid; i < P_LEN; i += 256) ps[i] = p[(size_t)g * P_LEN + i];
    __syncthreads();
    for (int o = tid; o < C3_OUT * C3_L; o += 256) {
        int oc = o / C3_L, pos = o % C3_L;
        float s = b3[oc];
        const float* w = w3 + oc * C3_K;
        int base = pos * C3_K;
        for (int k = 0; k < C3_K; ++k) s += ps[base + k] * w[k];
        h1s[o] = fmaxf(s, 0.0f);
    }
    __syncthreads();
    if (tid < C3_OUT * P2_L) {
        int oc = tid / P2_L, pos = tid % P2_L;
        h2s[tid] = fmaxf(h1s[oc * C3_L + 2 * pos], h1s[oc * C3_L + 2 * pos + 1]);
    }
    __syncthreads();
    if (tid < C4_OUT * C4_L) {
        int oc = tid / C4_L, pos = tid % C4_L;
        float s = b4[oc];
        for (int ic = 0; ic < C3_OUT; ++ic)
#pragma unroll
            for (int k = 0; k < C4_K; ++k)
                s += h2s[ic * P2_L + pos + k] * w4[oc * C3_OUT * C4_K + ic * C4_K + k];
        h3s[oc * C4_L + pos] = fmaxf(s, 0.0f);
    }
    __syncthreads();
    if (tid < FC1_OUT) {
        float s = fb1[tid];
        for (int i = 0; i < FC1_IN; ++i) s += h3s[i] * fw1[i * FC1_OUT + tid];
        float v = fmaxf(s, 0.0f);
        lls[tid] = v;
        out[2 * B_GRAPHS * NUM_CLASSES + (size_t)g * FC1_OUT + tid] = v;
    }
    __syncthreads();
    if (tid < NUM_CLASSES) {
        float s = fb2[tid];
        for (int j = 0; j < FC1_OUT; ++j) s += lls[j] * fw2[j * NUM_CLASSES + tid];
        outs[tid] = s;
        out[B_GRAPHS * NUM_CLASSES + (size_t)g * NUM_CLASSES + tid] = s;
    }
    __syncthreads();
    if (tid < NUM_CLASSES) {
        float m = -INFINITY;
        for (int k2 = 0; k2 < NUM_CLASSES; ++k2) m = fmaxf(m, outs[k2]);
        float se = 0.0f;
        for (int k2 = 0; k2 < NUM_CLASSES; ++k2) se += expf(outs[k2] - m);
        out[(size_t)g * NUM_CLASSES + tid] = outs[tid] - m - logf(se);
    }
}

extern "C" void kernel_launch(void* const* d_in, const int* in_sizes, int n_in,
                              void* d_out, int out_size, void* d_ws, size_t ws_size,
                              hipStream_t stream) {
    const float* x   = (const float*)d_in[0];
    const int*   ei  = (const int*)d_in[1];
    const int*   row = ei;
    const int*   col = ei + N_EDGES;
    const int*   bat = (const int*)d_in[2];
    const float* W1  = (const float*)d_in[4];
    const float* b1  = (const float*)d_in[5];
    const float* W2  = (const float*)d_in[6];
    const float* b2  = (const float*)d_in[7];
    const float* w3  = (const float*)d_in[8];
    const float* b3  = (const float*)d_in[9];
    const float* w4  = (const float*)d_in[10];
    const float* b4  = (const float*)d_in[11];
    const float* fw1 = (const float*)d_in[12];
    const float* fb1 = (const float*)d_in[13];
    const float* fw2 = (const float*)d_in[14];
    const float* fb2 = (const float*)d_in[15];

    char* wsb = (char*)d_ws;
    float* xw1    = (float*)wsb;                      wsb += (size_t)N_NODES * H1C * 4;  // 25.6 MB
    float* x1     = (float*)wsb;                      wsb += (size_t)N_NODES * H1C * 4;  // 25.6 MB
    int2*  edata  = (int2*)wsb;                       wsb += (size_t)N_EDGES * 8;        // 25.6 MB
    int*   cnt    = (int*)wsb;                        wsb += (size_t)N_NODES * 4;
    int*   rowptr = (int*)wsb;                        wsb += (size_t)(N_NODES + 1) * 4;
    int*   wptr   = (int*)wsb;                        wsb += (size_t)N_NODES * 4;
    int*   bsum   = (int*)wsb;                        wsb += (size_t)NSB * 4;
    float* dis    = (float*)wsb;                      wsb += (size_t)N_NODES * 4;
    float* xw2    = (float*)wsb;                      wsb += (size_t)N_NODES * 4;
    float* x2     = (float*)wsb;                      wsb += (size_t)N_NODES * 4;
    float* score  = (float*)wsb;                      wsb += (size_t)N_NODES * 4;
    float* p      = (float*)wsb;                      wsb += (size_t)B_GRAPHS * P_LEN * 4;
    float* outp   = (float*)d_out;

    hipMemsetAsync(cnt, 0, (size_t)N_NODES * 4, stream);
    hipMemsetAsync(p, 0, (size_t)B_GRAPHS * P_LEN * 4, stream);

    k_hist<<<(N_EDGES + 255) / 256, 256, 0, stream>>>(row, col, cnt);
    k_dis<<<(N_NODES + 255) / 256, 256, 0, stream>>>(cnt, dis);
    k_bsum<<<NSB, 256, 0, stream>>>(cnt, bsum);
    k_scanb<<<1, 512, 0, stream>>>(bsum);
    k_rowptr<<<NSB, 256, 0, stream>>>(cnt, bsum, rowptr, wptr);
    k_scatter<<<(N_EDGES + 255) / 256, 256, 0, stream>>>(row, col, dis, wptr, edata);
    k_xw1<<<(N_NODES + ROWS_PB - 1) / ROWS_PB, 256, 0, stream>>>(x, W1, xw1);
    k_agg1f<<<(N_NODES + 3) / 4, 256, 0, stream>>>(rowptr, edata, xw1, dis, b1, W2, x1, xw2);
    k_agg2f<<<(N_NODES + 3) / 4, 256, 0, stream>>>(rowptr, edata, xw2, dis, b2, x2, score);
    k_pool<<<B_GRAPHS, 256, 0, stream>>>(bat, x1, x2, score, p);
    k_head<<<B_GRAPHS, 256, 0, stream>>>(p, w3, b3, w4, b4, fw1, fb1, fw2, fb2, outp);
}

// Round 4
// 676.027 us; speedup vs baseline: 2.0540x; 1.1244x over previous
//
#include <hip/hip_runtime.h>
#include <math.h>

#define N_NODES 100000
#define N_EDGES 3200000
#define B_GRAPHS 500
#define K_TOP 30
#define F_INN 128
#define H1C 64
#define NUM_CLASSES 18
#define XC 65               // H1 + 1
#define P_LEN (K_TOP * XC)  // 1950
#define C3_OUT 16
#define C3_K 97
#define C3_L 20
#define P2_L 10
#define C4_OUT 32
#define C4_K 5
#define C4_L 6
#define FC1_IN 192
#define FC1_OUT 128
#define ROWS_PB 16
#define NSB ((N_NODES + 255) / 256)   // 391 scan blocks

// ---------------- histogram of destination degree (non-self edges) ----------------
__global__ void k_hist(const int* __restrict__ row, const int* __restrict__ col,
                       int* __restrict__ cnt) {
    int e = blockIdx.x * blockDim.x + threadIdx.x;
    if (e < N_EDGES) {
        int r = row[e], c = col[e];
        if (r != c) atomicAdd(&cnt[c], 1);
    }
}

// ---------------- dis = rsqrt(deg + 1) ----------------
__global__ void k_dis(const int* __restrict__ cnt, float* __restrict__ dis) {
    int n = blockIdx.x * blockDim.x + threadIdx.x;
    if (n < N_NODES) dis[n] = rsqrtf((float)cnt[n] + 1.0f);
}

// ---------------- scan stage 1: per-block sums ----------------
__global__ __launch_bounds__(256) void k_bsum(const int* __restrict__ cnt,
                                              int* __restrict__ bsum) {
    __shared__ int s[256];
    int b = blockIdx.x, t = threadIdx.x;
    int i = b * 256 + t;
    s[t] = (i < N_NODES) ? cnt[i] : 0;
    __syncthreads();
    for (int off = 128; off; off >>= 1) {
        if (t < off) s[t] += s[t + off];
        __syncthreads();
    }
    if (t == 0) bsum[b] = s[0];
}

// ---------------- scan stage 2: exclusive scan of 391 block sums ----------------
__global__ __launch_bounds__(512) void k_scanb(int* __restrict__ bsum) {
    __shared__ int s[512];
    int t = threadIdx.x;
    int v = (t < NSB) ? bsum[t] : 0;
    s[t] = v;
    __syncthreads();
    for (int off = 1; off < 512; off <<= 1) {
        int add = (t >= off) ? s[t - off] : 0;
        __syncthreads();
        s[t] += add;
        __syncthreads();
    }
    if (t < NSB) bsum[t] = s[t] - v;
}

// ---------------- scan stage 3: in-block scan + offset -> rowptr, wptr ----------------
__global__ __launch_bounds__(256) void k_rowptr(const int* __restrict__ cnt,
                                                const int* __restrict__ bsum,
                                                int* __restrict__ rowptr,
                                                int* __restrict__ wptr) {
    __shared__ int s[256];
    int b = blockIdx.x, t = threadIdx.x;
    int i = b * 256 + t;
    int v = (i < N_NODES) ? cnt[i] : 0;
    s[t] = v;
    __syncthreads();
    for (int off = 1; off < 256; off <<= 1) {
        int add = (t >= off) ? s[t - off] : 0;
        __syncthreads();
        s[t] += add;
        __syncthreads();
    }
    int ex = s[t] - v;
    int base = bsum[b];
    if (i < N_NODES) {
        rowptr[i] = base + ex;
        wptr[i] = base + ex;
        if (i == N_NODES - 1) rowptr[N_NODES] = base + ex + v;
    }
}

// ---------------- scatter edges into CSR-by-col: edata[pos] = {row, coef} ----------------
__global__ void k_scatter(const int* __restrict__ row, const int* __restrict__ col,
                          const float* __restrict__ dis, int* __restrict__ wptr,
                          int2* __restrict__ edata) {
    int e = blockIdx.x * blockDim.x + threadIdx.x;
    if (e < N_EDGES) {
        int r = row[e], c = col[e];
        if (r != c) {
            int pos = atomicAdd(&wptr[c], 1);
            float cf = dis[r] * dis[c];
            edata[pos] = make_int2(r, __float_as_int(cf));
        }
    }
}

// ---------------- xw1 = x (N,128) @ W1 (128,64) ----------------
__global__ __launch_bounds__(256) void k_xw1(const float* __restrict__ x,
                                             const float* __restrict__ W1,
                                             float* __restrict__ xw) {
    __shared__ float ws[F_INN * H1C];     // 32 KB
    __shared__ float xs[ROWS_PB * F_INN]; // 8 KB
    int tid = threadIdx.x;
    for (int i = tid; i < F_INN * H1C; i += 256) ws[i] = W1[i];
    int row0 = blockIdx.x * ROWS_PB;
    for (int i = tid; i < ROWS_PB * F_INN; i += 256) {
        int r = row0 + i / F_INN;
        xs[i] = (r < N_NODES) ? x[(size_t)r * F_INN + (i % F_INN)] : 0.0f;
    }
    __syncthreads();
    int c = tid & 63;
    int rb = tid >> 6;
    float acc[4] = {0.f, 0.f, 0.f, 0.f};
    for (int k = 0; k < F_INN; ++k) {
        float wv = ws[k * H1C + c];
#pragma unroll
        for (int i = 0; i < 4; ++i)
            acc[i] += xs[(rb + i * 4) * F_INN + k] * wv;
    }
#pragma unroll
    for (int i = 0; i < 4; ++i) {
        int r = row0 + rb + i * 4;
        if (r < N_NODES) xw[(size_t)r * H1C + c] = acc[i];
    }
}

// ------- conv1 gather-aggregate, float4 per lane, 4 edges per wave-load -------
// wave per node; group g (16 lanes) covers edge e0+g; lane loads 16B of the row.
__global__ __launch_bounds__(256) void k_agg1f(const int* __restrict__ rowptr,
                                               const int2* __restrict__ edata,
                                               const float* __restrict__ xw,
                                               const float* __restrict__ dis,
                                               const float* __restrict__ b1,
                                               const float* __restrict__ W2,
                                               float* __restrict__ x1,
                                               float* __restrict__ xw2) {
    int wid = blockIdx.x * 4 + (threadIdx.x >> 6);
    int lane = threadIdx.x & 63;
    if (wid >= N_NODES) return;
    int grp = lane >> 4;      // 0..3
    int sub = lane & 15;      // 0..15
    int base = rowptr[wid], endp = rowptr[wid + 1];
    float4 acc = make_float4(0.f, 0.f, 0.f, 0.f);
    for (int e0 = base; e0 < endp; e0 += 8) {
        int idx0 = e0 + grp;
        int idx1 = e0 + 4 + grp;
        int2 ed0 = (idx0 < endp) ? edata[idx0] : make_int2(wid, 0);
        int2 ed1 = (idx1 < endp) ? edata[idx1] : make_int2(wid, 0);
        float4 v0 = ((const float4*)(xw + (size_t)ed0.x * H1C))[sub];
        float4 v1 = ((const float4*)(xw + (size_t)ed1.x * H1C))[sub];
        float c0 = __int_as_float(ed0.y);
        float c1 = __int_as_float(ed1.y);
        acc.x += v0.x * c0 + v1.x * c1;
        acc.y += v0.y * c0 + v1.y * c1;
        acc.z += v0.z * c0 + v1.z * c1;
        acc.w += v0.w * c0 + v1.w * c1;
    }
    // combine the 4 group partials: channels [4*sub,4*sub+4) live in lanes sub+16g
    acc.x += __shfl_xor(acc.x, 16); acc.x += __shfl_xor(acc.x, 32);
    acc.y += __shfl_xor(acc.y, 16); acc.y += __shfl_xor(acc.y, 32);
    acc.z += __shfl_xor(acc.z, 16); acc.z += __shfl_xor(acc.z, 32);
    acc.w += __shfl_xor(acc.w, 16); acc.w += __shfl_xor(acc.w, 32);
    if (grp == 0) {
        float d = dis[wid];
        float d2 = d * d;
        float4 own = ((const float4*)(xw + (size_t)wid * H1C))[sub];
        float4 bb = ((const float4*)b1)[sub];
        float4 r;
        r.x = tanhf(acc.x + own.x * d2 + bb.x);
        r.y = tanhf(acc.y + own.y * d2 + bb.y);
        r.z = tanhf(acc.z + own.z * d2 + bb.z);
        r.w = tanhf(acc.w + own.w * d2 + bb.w);
        ((float4*)(x1 + (size_t)wid * H1C))[sub] = r;
        float4 w2v = ((const float4*)W2)[sub];
        float s = r.x * w2v.x + r.y * w2v.y + r.z * w2v.z + r.w * w2v.w;
        s += __shfl_xor(s, 8);
        s += __shfl_xor(s, 4);
        s += __shfl_xor(s, 2);
        s += __shfl_xor(s, 1);
        if (sub == 0) xw2[wid] = s;
    }
}

// ------- conv2 gather-aggregate (scalar) + tanh + score (wave per node) -------
__global__ __launch_bounds__(256) void k_agg2f(const int* __restrict__ rowptr,
                                               const int2* __restrict__ edata,
                                               const float* __restrict__ xw2,
                                               const float* __restrict__ dis,
                                               const float* __restrict__ b2,
                                               float* __restrict__ x2,
                                               float* __restrict__ score) {
    int wid = blockIdx.x * 4 + (threadIdx.x >> 6);
    int lane = threadIdx.x & 63;
    if (wid >= N_NODES) return;
    int base = rowptr[wid], endp = rowptr[wid + 1];
    float acc = 0.0f;
    for (int idx = base + lane; idx < endp; idx += 64) {
        int2 ed = edata[idx];
        acc += xw2[ed.x] * __int_as_float(ed.y);
    }
    for (int off = 32; off; off >>= 1) acc += __shfl_xor(acc, off);
    if (lane == 0) {
        float d = dis[wid];
        float v = tanhf(acc + xw2[wid] * d * d + b2[0]);
        x2[wid] = v;
        score[wid] = v;
    }
}

// ---------------- sort-pool: top-30 per graph by (score desc, idx asc) ----------------
__global__ __launch_bounds__(256) void k_pool(const int* __restrict__ batch,
                                              const float* __restrict__ x1,
                                              const float* __restrict__ x2,
                                              float* score, float* __restrict__ p) {
    __shared__ unsigned long long red[256];
    __shared__ int s_start, s_end;
    int g = blockIdx.x;
    int tid = threadIdx.x;
    if (tid == 0) {
        int lo = 0, hi = N_NODES;
        while (lo < hi) { int m = (lo + hi) >> 1; if (batch[m] < g) lo = m + 1; else hi = m; }
        s_start = lo;
        hi = N_NODES;
        while (lo < hi) { int m = (lo + hi) >> 1; if (batch[m] < g + 1) lo = m + 1; else hi = m; }
        s_end = lo;
    }
    __syncthreads();
    int start = s_start, end = s_end;
    int count = end - start;
    int kk = count < K_TOP ? count : K_TOP;
    for (int j = 0; j < kk; ++j) {
        unsigned long long best = 0ULL;
        for (int n = start + tid; n < end; n += 256) {
            float s = score[n];
            unsigned int bits = __float_as_uint(s);
            unsigned int u = (bits & 0x80000000u) ? ~bits : (bits | 0x80000000u);
            unsigned long long key =
                ((unsigned long long)u << 32) | (unsigned int)(~(unsigned int)n);
            if (key > best) best = key;
        }
        red[tid] = best;
        __syncthreads();
        for (int off = 128; off; off >>= 1) {
            if (tid < off) { if (red[tid + off] > red[tid]) red[tid] = red[tid + off]; }
            __syncthreads();
        }
        int node = (int)(~(unsigned int)(red[0] & 0xFFFFFFFFULL));
        if (tid < 64)
            p[(size_t)g * P_LEN + j * XC + tid] = x1[(size_t)node * H1C + tid];
        else if (tid == 64)
            p[(size_t)g * P_LEN + j * XC + 64] = x2[node];
        if (tid == 0) score[node] = -INFINITY;
        __syncthreads();
    }
}

// ---------------- head ----------------
__global__ __launch_bounds__(256) void k_head(const float* __restrict__ p,
                                              const float* __restrict__ w3, const float* __restrict__ b3,
                                              const float* __restrict__ w4, const float* __restrict__ b4,
                                              const float* __restrict__ fw1, const float* __restrict__ fb1,
                                              const float* __restrict__ fw2, const float* __restrict__ fb2,
                                              float* __restrict__ out) {
    __shared__ float ps[P_LEN];
    __shared__ float h1s[C3_OUT * C3_L];
    __shared__ float h2s[C3_OUT * P2_L];
    __shared__ float h3s[FC1_IN];
    __shared__ float lls[FC1_OUT];
    __shared__ float outs[NUM_CLASSES];
    int g = blockIdx.x, tid = threadIdx.x;
    for (int i = tid; i < P_LEN; i += 256) ps[i] = p[(size_t)g * P_LEN + i];
    __syncthreads();
    for (int o = tid; o < C3_OUT * C3_L; o += 256) {
        int oc = o / C3_L, pos = o % C3_L;
        float s = b3[oc];
        const float* w = w3 + oc * C3_K;
        int base = pos * C3_K;
        for (int k = 0; k < C3_K; ++k) s += ps[base + k] * w[k];
        h1s[o] = fmaxf(s, 0.0f);
    }
    __syncthreads();
    if (tid < C3_OUT * P2_L) {
        int oc = tid / P2_L, pos = tid % P2_L;
        h2s[tid] = fmaxf(h1s[oc * C3_L + 2 * pos], h1s[oc * C3_L + 2 * pos + 1]);
    }
    __syncthreads();
    if (tid < C4_OUT * C4_L) {
        int oc = tid / C4_L, pos = tid % C4_L;
        float s = b4[oc];
        for (int ic = 0; ic < C3_OUT; ++ic)
#pragma unroll
            for (int k = 0; k < C4_K; ++k)
                s += h2s[ic * P2_L + pos + k] * w4[oc * C3_OUT * C4_K + ic * C4_K + k];
        h3s[oc * C4_L + pos] = fmaxf(s, 0.0f);
    }
    __syncthreads();
    if (tid < FC1_OUT) {
        float s = fb1[tid];
        for (int i = 0; i < FC1_IN; ++i) s += h3s[i] * fw1[i * FC1_OUT + tid];
        float v = fmaxf(s, 0.0f);
        lls[tid] = v;
        out[2 * B_GRAPHS * NUM_CLASSES + (size_t)g * FC1_OUT + tid] = v;
    }
    __syncthreads();
    if (tid < NUM_CLASSES) {
        float s = fb2[tid];
        for (int j = 0; j < FC1_OUT; ++j) s += lls[j] * fw2[j * NUM_CLASSES + tid];
        outs[tid] = s;
        out[B_GRAPHS * NUM_CLASSES + (size_t)g * NUM_CLASSES + tid] = s;
    }
    __syncthreads();
    if (tid < NUM_CLASSES) {
        float m = -INFINITY;
        for (int k2 = 0; k2 < NUM_CLASSES; ++k2) m = fmaxf(m, outs[k2]);
        float se = 0.0f;
        for (int k2 = 0; k2 < NUM_CLASSES; ++k2) se += expf(outs[k2] - m);
        out[(size_t)g * NUM_CLASSES + tid] = outs[tid] - m - logf(se);
    }
}

extern "C" void kernel_launch(void* const* d_in, const int* in_sizes, int n_in,
                              void* d_out, int out_size, void* d_ws, size_t ws_size,
                              hipStream_t stream) {
    const float* x   = (const float*)d_in[0];
    const int*   ei  = (const int*)d_in[1];
    const int*   row = ei;
    const int*   col = ei + N_EDGES;
    const int*   bat = (const int*)d_in[2];
    const float* W1  = (const float*)d_in[4];
    const float* b1  = (const float*)d_in[5];
    const float* W2  = (const float*)d_in[6];
    const float* b2  = (const float*)d_in[7];
    const float* w3  = (const float*)d_in[8];
    const float* b3  = (const float*)d_in[9];
    const float* w4  = (const float*)d_in[10];
    const float* b4  = (const float*)d_in[11];
    const float* fw1 = (const float*)d_in[12];
    const float* fb1 = (const float*)d_in[13];
    const float* fw2 = (const float*)d_in[14];
    const float* fb2 = (const float*)d_in[15];

    char* wsb = (char*)d_ws;
    float* xw1    = (float*)wsb;                      wsb += (size_t)N_NODES * H1C * 4;  // 25.6 MB
    float* x1     = (float*)wsb;                      wsb += (size_t)N_NODES * H1C * 4;  // 25.6 MB
    int2*  edata  = (int2*)wsb;                       wsb += (size_t)N_EDGES * 8;        // 25.6 MB
    int*   cnt    = (int*)wsb;                        wsb += (size_t)N_NODES * 4;
    int*   rowptr = (int*)wsb;                        wsb += (size_t)(N_NODES + 1) * 4;
    int*   wptr   = (int*)wsb;                        wsb += (size_t)N_NODES * 4;
    int*   bsum   = (int*)wsb;                        wsb += (size_t)NSB * 4;
    float* dis    = (float*)wsb;                      wsb += (size_t)N_NODES * 4;
    float* xw2    = (float*)wsb;                      wsb += (size_t)N_NODES * 4;
    float* x2     = (float*)wsb;                      wsb += (size_t)N_NODES * 4;
    float* score  = (float*)wsb;                      wsb += (size_t)N_NODES * 4;
    float* p      = (float*)wsb;                      wsb += (size_t)B_GRAPHS * P_LEN * 4;
    float* outp   = (float*)d_out;

    hipMemsetAsync(cnt, 0, (size_t)N_NODES * 4, stream);
    hipMemsetAsync(p, 0, (size_t)B_GRAPHS * P_LEN * 4, stream);

    k_hist<<<(N_EDGES + 255) / 256, 256, 0, stream>>>(row, col, cnt);
    k_dis<<<(N_NODES + 255) / 256, 256, 0, stream>>>(cnt, dis);
    k_bsum<<<NSB, 256, 0, stream>>>(cnt, bsum);
    k_scanb<<<1, 512, 0, stream>>>(bsum);
    k_rowptr<<<NSB, 256, 0, stream>>>(cnt, bsum, rowptr, wptr);
    k_scatter<<<(N_EDGES + 255) / 256, 256, 0, stream>>>(row, col, dis, wptr, edata);
    k_xw1<<<(N_NODES + ROWS_PB - 1) / ROWS_PB, 256, 0, stream>>>(x, W1, xw1);
    k_agg1f<<<(N_NODES + 3) / 4, 256, 0, stream>>>(rowptr, edata, xw1, dis, b1, W2, x1, xw2);
    k_agg2f<<<(N_NODES + 3) / 4, 256, 0, stream>>>(rowptr, edata, xw2, dis, b2, x2, score);
    k_pool<<<B_GRAPHS, 256, 0, stream>>>(bat, x1, x2, score, p);
    k_head<<<B_GRAPHS, 256, 0, stream>>>(p, w3, b3, w4, b4, fw1, fb1, fw2, fb2, outp);
}

// Round 5
// 528.740 us; speedup vs baseline: 2.6261x; 1.2786x over previous
//
#include <hip/hip_runtime.h>
#include <math.h>

#define N_NODES 100000
#define N_EDGES 3200000
#define B_GRAPHS 500
#define K_TOP 30
#define F_INN 128
#define H1C 64
#define NUM_CLASSES 18
#define XC 65               // H1 + 1
#define P_LEN (K_TOP * XC)  // 1950
#define C3_OUT 16
#define C3_K 97
#define C3_L 20
#define P2_L 10
#define C4_OUT 32
#define C4_K 5
#define C4_L 6
#define FC1_IN 192
#define FC1_OUT 128
#define ROWS_PB 16

#define BK_SHIFT 7
#define BK_NODES 128                               // nodes per bucket
#define NBKT ((N_NODES + BK_NODES - 1) / BK_NODES) // 782
#define MS_EPT 16                                  // edges per thread in mscatter
#define MS_EPB (256 * MS_EPT)                      // 4096 edges per block

// ---------------- bucket histogram (non-self edges) ----------------
__global__ __launch_bounds__(256) void k_bcount(const int* __restrict__ row,
                                                const int* __restrict__ col,
                                                int* __restrict__ bcount) {
    __shared__ int hist[NBKT];
    int tid = threadIdx.x;
    for (int i = tid; i < NBKT; i += 256) hist[i] = 0;
    __syncthreads();
    int base = blockIdx.x * 2048;
    for (int j = 0; j < 8; ++j) {
        int e = base + j * 256 + tid;
        if (e < N_EDGES) {
            int r = row[e], c = col[e];
            if (r != c) atomicAdd(&hist[c >> BK_SHIFT], 1);
        }
    }
    __syncthreads();
    for (int i = tid; i < NBKT; i += 256)
        if (hist[i]) atomicAdd(&bcount[i], hist[i]);
}

// ---------------- scan bucket counts -> bbase (NBKT+1), gcur ----------------
__global__ __launch_bounds__(1024) void k_bscan(const int* __restrict__ bcount,
                                                int* __restrict__ bbase,
                                                int* __restrict__ gcur) {
    __shared__ int s[1024];
    int t = threadIdx.x;
    int v = (t < NBKT) ? bcount[t] : 0;
    s[t] = v;
    __syncthreads();
    for (int off = 1; off < 1024; off <<= 1) {
        int add = (t >= off) ? s[t - off] : 0;
        __syncthreads();
        s[t] += add;
        __syncthreads();
    }
    if (t < NBKT) {
        int ex = s[t] - v;
        bbase[t] = ex;
        gcur[t] = ex;
        if (t == NBKT - 1) bbase[NBKT] = s[t];
    }
}

// ------- multi-split scatter: ebkt[slot] = (row<<7 | col_local), dense per bucket -------
__global__ __launch_bounds__(256) void k_mscatter(const int* __restrict__ row,
                                                  const int* __restrict__ col,
                                                  int* __restrict__ gcur,
                                                  unsigned int* __restrict__ ebkt) {
    __shared__ int hist[NBKT];
    __shared__ int base[NBKT];
    int tid = threadIdx.x;
    for (int i = tid; i < NBKT; i += 256) hist[i] = 0;
    __syncthreads();
    unsigned int pk[MS_EPT];   // (bucket<<12) | rank, or sentinel
    unsigned int pay[MS_EPT];  // (row<<7) | col_local
    int e0 = blockIdx.x * MS_EPB;
#pragma unroll
    for (int j = 0; j < MS_EPT; ++j) {
        int e = e0 + j * 256 + tid;
        pk[j] = 0xFFFFFFFFu;
        if (e < N_EDGES) {
            int r = row[e], c = col[e];
            if (r != c) {
                int b = c >> BK_SHIFT;
                int rank = atomicAdd(&hist[b], 1);
                pk[j] = ((unsigned int)b << 12) | (unsigned int)rank;
                pay[j] = ((unsigned int)r << BK_SHIFT) | (unsigned int)(c & (BK_NODES - 1));
            }
        }
    }
    __syncthreads();
    for (int i = tid; i < NBKT; i += 256)
        base[i] = hist[i] ? atomicAdd(&gcur[i], hist[i]) : 0;
    __syncthreads();
#pragma unroll
    for (int j = 0; j < MS_EPT; ++j) {
        if (pk[j] != 0xFFFFFFFFu) {
            int b = pk[j] >> 12;
            int rank = pk[j] & 0xFFF;
            ebkt[base[b] + rank] = pay[j];
        }
    }
}

// ------- per-bucket: deg (dense) + rowptr (dense) from bucket records -------
__global__ __launch_bounds__(256) void k_degtile(const unsigned int* __restrict__ ebkt,
                                                 const int* __restrict__ bbase,
                                                 int* __restrict__ deg,
                                                 int* __restrict__ rowptr) {
    __shared__ int cnt[BK_NODES];
    __shared__ int s[256];
    int b = blockIdx.x, t = threadIdx.x;
    if (t < BK_NODES) cnt[t] = 0;
    __syncthreads();
    int lo = bbase[b], hi = bbase[b + 1];
    for (int i = lo + t; i < hi; i += 256)
        atomicAdd(&cnt[ebkt[i] & (BK_NODES - 1)], 1);
    __syncthreads();
    int v = (t < BK_NODES) ? cnt[t] : 0;
    s[t] = v;
    __syncthreads();
    for (int off = 1; off < BK_NODES; off <<= 1) {
        int add = (t >= off) ? s[t - off] : 0;
        __syncthreads();
        s[t] += add;
        __syncthreads();
    }
    if (t < BK_NODES) {
        int node = b * BK_NODES + t;
        if (node < N_NODES) {
            deg[node] = v;
            rowptr[node] = lo + (s[t] - v);
            if (node == N_NODES - 1) rowptr[N_NODES] = lo + s[t];
        }
    }
}

// ---------------- dis = rsqrt(deg + 1) ----------------
__global__ void k_dis(const int* __restrict__ deg, float* __restrict__ dis) {
    int n = blockIdx.x * blockDim.x + threadIdx.x;
    if (n < N_NODES) dis[n] = rsqrtf((float)deg[n] + 1.0f);
}

// ------- per-bucket: final CSR edata {row, coef} at per-node slots, dense span -------
__global__ __launch_bounds__(256) void k_csrscatter(const unsigned int* __restrict__ ebkt,
                                                    const int* __restrict__ bbase,
                                                    const float* __restrict__ dis,
                                                    int2* __restrict__ edata) {
    __shared__ int cnt[BK_NODES];
    __shared__ int s[256];
    __shared__ int cur[BK_NODES];
    __shared__ float disl[BK_NODES];
    int b = blockIdx.x, t = threadIdx.x;
    if (t < BK_NODES) {
        cnt[t] = 0;
        int node = b * BK_NODES + t;
        disl[t] = (node < N_NODES) ? dis[node] : 1.0f;
    }
    __syncthreads();
    int lo = bbase[b], hi = bbase[b + 1];
    for (int i = lo + t; i < hi; i += 256)
        atomicAdd(&cnt[ebkt[i] & (BK_NODES - 1)], 1);
    __syncthreads();
    int v = (t < BK_NODES) ? cnt[t] : 0;
    s[t] = v;
    __syncthreads();
    for (int off = 1; off < BK_NODES; off <<= 1) {
        int add = (t >= off) ? s[t - off] : 0;
        __syncthreads();
        s[t] += add;
        __syncthreads();
    }
    if (t < BK_NODES) cur[t] = s[t] - v;   // exclusive base within bucket
    __syncthreads();
    for (int i = lo + t; i < hi; i += 256) {
        unsigned int pk = ebkt[i];
        int cl = pk & (BK_NODES - 1);
        int r = pk >> BK_SHIFT;
        int slot = atomicAdd(&cur[cl], 1);
        float cf = dis[r] * disl[cl];
        edata[lo + slot] = make_int2(r, __float_as_int(cf));
    }
}

// ---------------- xw1 = x (N,128) @ W1 (128,64) ----------------
__global__ __launch_bounds__(256) void k_xw1(const float* __restrict__ x,
                                             const float* __restrict__ W1,
                                             float* __restrict__ xw) {
    __shared__ float ws[F_INN * H1C];     // 32 KB
    __shared__ float xs[ROWS_PB * F_INN]; // 8 KB
    int tid = threadIdx.x;
    for (int i = tid; i < F_INN * H1C; i += 256) ws[i] = W1[i];
    int row0 = blockIdx.x * ROWS_PB;
    for (int i = tid; i < ROWS_PB * F_INN; i += 256) {
        int r = row0 + i / F_INN;
        xs[i] = (r < N_NODES) ? x[(size_t)r * F_INN + (i % F_INN)] : 0.0f;
    }
    __syncthreads();
    int c = tid & 63;
    int rb = tid >> 6;
    float acc[4] = {0.f, 0.f, 0.f, 0.f};
    for (int k = 0; k < F_INN; ++k) {
        float wv = ws[k * H1C + c];
#pragma unroll
        for (int i = 0; i < 4; ++i)
            acc[i] += xs[(rb + i * 4) * F_INN + k] * wv;
    }
#pragma unroll
    for (int i = 0; i < 4; ++i) {
        int r = row0 + rb + i * 4;
        if (r < N_NODES) xw[(size_t)r * H1C + c] = acc[i];
    }
}

// ------- conv1 gather-aggregate, float4 per lane, 4 edges per wave-load -------
__global__ __launch_bounds__(256) void k_agg1f(const int* __restrict__ rowptr,
                                               const int2* __restrict__ edata,
                                               const float* __restrict__ xw,
                                               const float* __restrict__ dis,
                                               const float* __restrict__ b1,
                                               const float* __restrict__ W2,
                                               float* __restrict__ x1,
                                               float* __restrict__ xw2) {
    int wid = blockIdx.x * 4 + (threadIdx.x >> 6);
    int lane = threadIdx.x & 63;
    if (wid >= N_NODES) return;
    int grp = lane >> 4;      // 0..3
    int sub = lane & 15;      // 0..15
    int base = rowptr[wid], endp = rowptr[wid + 1];
    float4 acc = make_float4(0.f, 0.f, 0.f, 0.f);
    for (int e0 = base; e0 < endp; e0 += 8) {
        int idx0 = e0 + grp;
        int idx1 = e0 + 4 + grp;
        int2 ed0 = (idx0 < endp) ? edata[idx0] : make_int2(wid, 0);
        int2 ed1 = (idx1 < endp) ? edata[idx1] : make_int2(wid, 0);
        float4 v0 = ((const float4*)(xw + (size_t)ed0.x * H1C))[sub];
        float4 v1 = ((const float4*)(xw + (size_t)ed1.x * H1C))[sub];
        float c0 = __int_as_float(ed0.y);
        float c1 = __int_as_float(ed1.y);
        acc.x += v0.x * c0 + v1.x * c1;
        acc.y += v0.y * c0 + v1.y * c1;
        acc.z += v0.z * c0 + v1.z * c1;
        acc.w += v0.w * c0 + v1.w * c1;
    }
    acc.x += __shfl_xor(acc.x, 16); acc.x += __shfl_xor(acc.x, 32);
    acc.y += __shfl_xor(acc.y, 16); acc.y += __shfl_xor(acc.y, 32);
    acc.z += __shfl_xor(acc.z, 16); acc.z += __shfl_xor(acc.z, 32);
    acc.w += __shfl_xor(acc.w, 16); acc.w += __shfl_xor(acc.w, 32);
    if (grp == 0) {
        float d = dis[wid];
        float d2 = d * d;
        float4 own = ((const float4*)(xw + (size_t)wid * H1C))[sub];
        float4 bb = ((const float4*)b1)[sub];
        float4 r;
        r.x = tanhf(acc.x + own.x * d2 + bb.x);
        r.y = tanhf(acc.y + own.y * d2 + bb.y);
        r.z = tanhf(acc.z + own.z * d2 + bb.z);
        r.w = tanhf(acc.w + own.w * d2 + bb.w);
        ((float4*)(x1 + (size_t)wid * H1C))[sub] = r;
        float4 w2v = ((const float4*)W2)[sub];
        float s = r.x * w2v.x + r.y * w2v.y + r.z * w2v.z + r.w * w2v.w;
        s += __shfl_xor(s, 8);
        s += __shfl_xor(s, 4);
        s += __shfl_xor(s, 2);
        s += __shfl_xor(s, 1);
        if (sub == 0) xw2[wid] = s;
    }
}

// ------- conv2 gather-aggregate (scalar) + tanh + score (wave per node) -------
__global__ __launch_bounds__(256) void k_agg2f(const int* __restrict__ rowptr,
                                               const int2* __restrict__ edata,
                                               const float* __restrict__ xw2,
                                               const float* __restrict__ dis,
                                               const float* __restrict__ b2,
                                               float* __restrict__ x2,
                                               float* __restrict__ score) {
    int wid = blockIdx.x * 4 + (threadIdx.x >> 6);
    int lane = threadIdx.x & 63;
    if (wid >= N_NODES) return;
    int base = rowptr[wid], endp = rowptr[wid + 1];
    float acc = 0.0f;
    for (int idx = base + lane; idx < endp; idx += 64) {
        int2 ed = edata[idx];
        acc += xw2[ed.x] * __int_as_float(ed.y);
    }
    for (int off = 32; off; off >>= 1) acc += __shfl_xor(acc, off);
    if (lane == 0) {
        float d = dis[wid];
        float v = tanhf(acc + xw2[wid] * d * d + b2[0]);
        x2[wid] = v;
        score[wid] = v;
    }
}

// ---------------- sort-pool: top-30 per graph by (score desc, idx asc) ----------------
__global__ __launch_bounds__(256) void k_pool(const int* __restrict__ batch,
                                              const float* __restrict__ x1,
                                              const float* __restrict__ x2,
                                              float* score, float* __restrict__ p) {
    __shared__ unsigned long long red[256];
    __shared__ int s_start, s_end;
    int g = blockIdx.x;
    int tid = threadIdx.x;
    if (tid == 0) {
        int lo = 0, hi = N_NODES;
        while (lo < hi) { int m = (lo + hi) >> 1; if (batch[m] < g) lo = m + 1; else hi = m; }
        s_start = lo;
        hi = N_NODES;
        while (lo < hi) { int m = (lo + hi) >> 1; if (batch[m] < g + 1) lo = m + 1; else hi = m; }
        s_end = lo;
    }
    __syncthreads();
    int start = s_start, end = s_end;
    int count = end - start;
    int kk = count < K_TOP ? count : K_TOP;
    for (int j = 0; j < kk; ++j) {
        unsigned long long best = 0ULL;
        for (int n = start + tid; n < end; n += 256) {
            float s = score[n];
            unsigned int bits = __float_as_uint(s);
            unsigned int u = (bits & 0x80000000u) ? ~bits : (bits | 0x80000000u);
            unsigned long long key =
                ((unsigned long long)u << 32) | (unsigned int)(~(unsigned int)n);
            if (key > best) best = key;
        }
        red[tid] = best;
        __syncthreads();
        for (int off = 128; off; off >>= 1) {
            if (tid < off) { if (red[tid + off] > red[tid]) red[tid] = red[tid + off]; }
            __syncthreads();
        }
        int node = (int)(~(unsigned int)(red[0] & 0xFFFFFFFFULL));
        if (tid < 64)
            p[(size_t)g * P_LEN + j * XC + tid] = x1[(size_t)node * H1C + tid];
        else if (tid == 64)
            p[(size_t)g * P_LEN + j * XC + 64] = x2[node];
        if (tid == 0) score[node] = -INFINITY;
        __syncthreads();
    }
}

// ---------------- head ----------------
__global__ __launch_bounds__(256) void k_head(const float* __restrict__ p,
                                              const float* __restrict__ w3, const float* __restrict__ b3,
                                              const float* __restrict__ w4, const float* __restrict__ b4,
                                              const float* __restrict__ fw1, const float* __restrict__ fb1,
                                              const float* __restrict__ fw2, const float* __restrict__ fb2,
                                              float* __restrict__ out) {
    __shared__ float ps[P_LEN];
    __shared__ float h1s[C3_OUT * C3_L];
    __shared__ float h2s[C3_OUT * P2_L];
    __shared__ float h3s[FC1_IN];
    __shared__ float lls[FC1_OUT];
    __shared__ float outs[NUM_CLASSES];
    int g = blockIdx.x, tid = threadIdx.x;
    for (int i = tid; i < P_LEN; i += 256) ps[i] = p[(size_t)g * P_LEN + i];
    __syncthreads();
    for (int o = tid; o < C3_OUT * C3_L; o += 256) {
        int oc = o / C3_L, pos = o % C3_L;
        float s = b3[oc];
        const float* w = w3 + oc * C3_K;
        int base = pos * C3_K;
        for (int k = 0; k < C3_K; ++k) s += ps[base + k] * w[k];
        h1s[o] = fmaxf(s, 0.0f);
    }
    __syncthreads();
    if (tid < C3_OUT * P2_L) {
        int oc = tid / P2_L, pos = tid % P2_L;
        h2s[tid] = fmaxf(h1s[oc * C3_L + 2 * pos], h1s[oc * C3_L + 2 * pos + 1]);
    }
    __syncthreads();
    if (tid < C4_OUT * C4_L) {
        int oc = tid / C4_L, pos = tid % C4_L;
        float s = b4[oc];
        for (int ic = 0; ic < C3_OUT; ++ic)
#pragma unroll
            for (int k = 0; k < C4_K; ++k)
                s += h2s[ic * P2_L + pos + k] * w4[oc * C3_OUT * C4_K + ic * C4_K + k];
        h3s[oc * C4_L + pos] = fmaxf(s, 0.0f);
    }
    __syncthreads();
    if (tid < FC1_OUT) {
        float s = fb1[tid];
        for (int i = 0; i < FC1_IN; ++i) s += h3s[i] * fw1[i * FC1_OUT + tid];
        float v = fmaxf(s, 0.0f);
        lls[tid] = v;
        out[2 * B_GRAPHS * NUM_CLASSES + (size_t)g * FC1_OUT + tid] = v;
    }
    __syncthreads();
    if (tid < NUM_CLASSES) {
        float s = fb2[tid];
        for (int j = 0; j < FC1_OUT; ++j) s += lls[j] * fw2[j * NUM_CLASSES + tid];
        outs[tid] = s;
        out[B_GRAPHS * NUM_CLASSES + (size_t)g * NUM_CLASSES + tid] = s;
    }
    __syncthreads();
    if (tid < NUM_CLASSES) {
        float m = -INFINITY;
        for (int k2 = 0; k2 < NUM_CLASSES; ++k2) m = fmaxf(m, outs[k2]);
        float se = 0.0f;
        for (int k2 = 0; k2 < NUM_CLASSES; ++k2) se += expf(outs[k2] - m);
        out[(size_t)g * NUM_CLASSES + tid] = outs[tid] - m - logf(se);
    }
}

extern "C" void kernel_launch(void* const* d_in, const int* in_sizes, int n_in,
                              void* d_out, int out_size, void* d_ws, size_t ws_size,
                              hipStream_t stream) {
    const float* x   = (const float*)d_in[0];
    const int*   ei  = (const int*)d_in[1];
    const int*   row = ei;
    const int*   col = ei + N_EDGES;
    const int*   bat = (const int*)d_in[2];
    const float* W1  = (const float*)d_in[4];
    const float* b1  = (const float*)d_in[5];
    const float* W2  = (const float*)d_in[6];
    const float* b2  = (const float*)d_in[7];
    const float* w3  = (const float*)d_in[8];
    const float* b3  = (const float*)d_in[9];
    const float* w4  = (const float*)d_in[10];
    const float* b4  = (const float*)d_in[11];
    const float* fw1 = (const float*)d_in[12];
    const float* fb1 = (const float*)d_in[13];
    const float* fw2 = (const float*)d_in[14];
    const float* fb2 = (const float*)d_in[15];

    char* wsb = (char*)d_ws;
    float* xw1    = (float*)wsb;                      wsb += (size_t)N_NODES * H1C * 4;  // 25.6 MB
    float* x1     = (float*)wsb;                      wsb += (size_t)N_NODES * H1C * 4;  // 25.6 MB
    int2*  edata  = (int2*)wsb;                       wsb += (size_t)N_EDGES * 8;        // 25.6 MB
    // ebkt aliases x1: consumed by k_csrscatter before k_agg1f writes x1
    unsigned int* ebkt = (unsigned int*)x1;
    int*   bcount = (int*)wsb;                        wsb += (size_t)NBKT * 4;
    int*   bbase  = (int*)wsb;                        wsb += (size_t)(NBKT + 1) * 4;
    int*   gcur   = (int*)wsb;                        wsb += (size_t)NBKT * 4;
    int*   deg    = (int*)wsb;                        wsb += (size_t)N_NODES * 4;
    int*   rowptr = (int*)wsb;                        wsb += (size_t)(N_NODES + 1) * 4;
    float* dis    = (float*)wsb;                      wsb += (size_t)N_NODES * 4;
    float* xw2    = (float*)wsb;                      wsb += (size_t)N_NODES * 4;
    float* x2     = (float*)wsb;                      wsb += (size_t)N_NODES * 4;
    float* score  = (float*)wsb;                      wsb += (size_t)N_NODES * 4;
    float* p      = (float*)wsb;                      wsb += (size_t)B_GRAPHS * P_LEN * 4;
    float* outp   = (float*)d_out;

    hipMemsetAsync(bcount, 0, (size_t)NBKT * 4, stream);
    hipMemsetAsync(p, 0, (size_t)B_GRAPHS * P_LEN * 4, stream);

    k_bcount<<<(N_EDGES + 2047) / 2048, 256, 0, stream>>>(row, col, bcount);
    k_bscan<<<1, 1024, 0, stream>>>(bcount, bbase, gcur);
    k_mscatter<<<(N_EDGES + MS_EPB - 1) / MS_EPB, 256, 0, stream>>>(row, col, gcur, ebkt);
    k_degtile<<<NBKT, 256, 0, stream>>>(ebkt, bbase, deg, rowptr);
    k_dis<<<(N_NODES + 255) / 256, 256, 0, stream>>>(deg, dis);
    k_csrscatter<<<NBKT, 256, 0, stream>>>(ebkt, bbase, dis, edata);
    k_xw1<<<(N_NODES + ROWS_PB - 1) / ROWS_PB, 256, 0, stream>>>(x, W1, xw1);
    k_agg1f<<<(N_NODES + 3) / 4, 256, 0, stream>>>(rowptr, edata, xw1, dis, b1, W2, x1, xw2);
    k_agg2f<<<(N_NODES + 3) / 4, 256, 0, stream>>>(rowptr, edata, xw2, dis, b2, x2, score);
    k_pool<<<B_GRAPHS, 256, 0, stream>>>(bat, x1, x2, score, p);
    k_head<<<B_GRAPHS, 256, 0, stream>>>(p, w3, b3, w4, b4, fw1, fb1, fw2, fb2, outp);
}

// Round 6
// 482.710 us; speedup vs baseline: 2.8766x; 1.0954x over previous
//
#include <hip/hip_runtime.h>
#include <math.h>

#define N_NODES 100000
#define N_EDGES 3200000
#define B_GRAPHS 500
#define K_TOP 30
#define F_INN 128
#define H1C 64
#define NUM_CLASSES 18
#define XC 65               // H1 + 1
#define P_LEN (K_TOP * XC)  // 1950
#define C3_OUT 16
#define C3_K 97
#define C3_L 20
#define P2_L 10
#define C4_OUT 32
#define C4_K 5
#define C4_L 6
#define FC1_IN 192
#define FC1_OUT 128
#define ROWS_PB 16

#define BK_SHIFT 7
#define BK_NODES 128                               // nodes per bucket
#define NBKT ((N_NODES + BK_NODES - 1) / BK_NODES) // 782
#define MS_EPT 16                                  // edges per thread in mscatter
#define MS_EPB (256 * MS_EPT)                      // 4096 edges per block

// bf16 helpers
static __device__ __forceinline__ unsigned short f2bf(float f) {
    unsigned int u = __float_as_uint(f);
    u += 0x7FFFu + ((u >> 16) & 1u);   // round to nearest even
    return (unsigned short)(u >> 16);
}
static __device__ __forceinline__ float bfl(unsigned int u) {   // low bf16
    return __uint_as_float(u << 16);
}
static __device__ __forceinline__ float bfh(unsigned int u) {   // high bf16
    return __uint_as_float(u & 0xFFFF0000u);
}

// ---------------- bucket histogram (non-self edges) ----------------
__global__ __launch_bounds__(256) void k_bcount(const int* __restrict__ row,
                                                const int* __restrict__ col,
                                                int* __restrict__ bcount) {
    __shared__ int hist[NBKT];
    int tid = threadIdx.x;
    for (int i = tid; i < NBKT; i += 256) hist[i] = 0;
    __syncthreads();
    int base = blockIdx.x * 2048;
    for (int j = 0; j < 8; ++j) {
        int e = base + j * 256 + tid;
        if (e < N_EDGES) {
            int r = row[e], c = col[e];
            if (r != c) atomicAdd(&hist[c >> BK_SHIFT], 1);
        }
    }
    __syncthreads();
    for (int i = tid; i < NBKT; i += 256)
        if (hist[i]) atomicAdd(&bcount[i], hist[i]);
}

// ---------------- scan bucket counts -> bbase (NBKT+1), gcur ----------------
__global__ __launch_bounds__(1024) void k_bscan(const int* __restrict__ bcount,
                                                int* __restrict__ bbase,
                                                int* __restrict__ gcur) {
    __shared__ int s[1024];
    int t = threadIdx.x;
    int v = (t < NBKT) ? bcount[t] : 0;
    s[t] = v;
    __syncthreads();
    for (int off = 1; off < 1024; off <<= 1) {
        int add = (t >= off) ? s[t - off] : 0;
        __syncthreads();
        s[t] += add;
        __syncthreads();
    }
    if (t < NBKT) {
        int ex = s[t] - v;
        bbase[t] = ex;
        gcur[t] = ex;
        if (t == NBKT - 1) bbase[NBKT] = s[t];
    }
}

// ------- multi-split scatter: ebkt[slot] = (row<<7 | col_local), dense per bucket -------
__global__ __launch_bounds__(256) void k_mscatter(const int* __restrict__ row,
                                                  const int* __restrict__ col,
                                                  int* __restrict__ gcur,
                                                  unsigned int* __restrict__ ebkt) {
    __shared__ int hist[NBKT];
    __shared__ int base[NBKT];
    int tid = threadIdx.x;
    for (int i = tid; i < NBKT; i += 256) hist[i] = 0;
    __syncthreads();
    unsigned int pk[MS_EPT];   // (bucket<<12) | rank, or sentinel
    unsigned int pay[MS_EPT];  // (row<<7) | col_local
    int e0 = blockIdx.x * MS_EPB;
#pragma unroll
    for (int j = 0; j < MS_EPT; ++j) {
        int e = e0 + j * 256 + tid;
        pk[j] = 0xFFFFFFFFu;
        if (e < N_EDGES) {
            int r = row[e], c = col[e];
            if (r != c) {
                int b = c >> BK_SHIFT;
                int rank = atomicAdd(&hist[b], 1);
                pk[j] = ((unsigned int)b << 12) | (unsigned int)rank;
                pay[j] = ((unsigned int)r << BK_SHIFT) | (unsigned int)(c & (BK_NODES - 1));
            }
        }
    }
    __syncthreads();
    for (int i = tid; i < NBKT; i += 256)
        base[i] = hist[i] ? atomicAdd(&gcur[i], hist[i]) : 0;
    __syncthreads();
#pragma unroll
    for (int j = 0; j < MS_EPT; ++j) {
        if (pk[j] != 0xFFFFFFFFu) {
            int b = pk[j] >> 12;
            int rank = pk[j] & 0xFFF;
            ebkt[base[b] + rank] = pay[j];
        }
    }
}

// ------- per-bucket: deg (dense) + rowptr (dense) from bucket records -------
__global__ __launch_bounds__(256) void k_degtile(const unsigned int* __restrict__ ebkt,
                                                 const int* __restrict__ bbase,
                                                 int* __restrict__ deg,
                                                 int* __restrict__ rowptr) {
    __shared__ int cnt[BK_NODES];
    __shared__ int s[256];
    int b = blockIdx.x, t = threadIdx.x;
    if (t < BK_NODES) cnt[t] = 0;
    __syncthreads();
    int lo = bbase[b], hi = bbase[b + 1];
    for (int i = lo + t; i < hi; i += 256)
        atomicAdd(&cnt[ebkt[i] & (BK_NODES - 1)], 1);
    __syncthreads();
    int v = (t < BK_NODES) ? cnt[t] : 0;
    s[t] = v;
    __syncthreads();
    for (int off = 1; off < BK_NODES; off <<= 1) {
        int add = (t >= off) ? s[t - off] : 0;
        __syncthreads();
        s[t] += add;
        __syncthreads();
    }
    if (t < BK_NODES) {
        int node = b * BK_NODES + t;
        if (node < N_NODES) {
            deg[node] = v;
            rowptr[node] = lo + (s[t] - v);
            if (node == N_NODES - 1) rowptr[N_NODES] = lo + s[t];
        }
    }
}

// ---------------- dis = rsqrt(deg + 1) ----------------
__global__ void k_dis(const int* __restrict__ deg, float* __restrict__ dis) {
    int n = blockIdx.x * blockDim.x + threadIdx.x;
    if (n < N_NODES) dis[n] = rsqrtf((float)deg[n] + 1.0f);
}

// ------- per-bucket: final CSR edata {row, coef} at per-node slots, dense span -------
__global__ __launch_bounds__(256) void k_csrscatter(const unsigned int* __restrict__ ebkt,
                                                    const int* __restrict__ bbase,
                                                    const float* __restrict__ dis,
                                                    int2* __restrict__ edata) {
    __shared__ int cnt[BK_NODES];
    __shared__ int s[256];
    __shared__ int cur[BK_NODES];
    __shared__ float disl[BK_NODES];
    int b = blockIdx.x, t = threadIdx.x;
    if (t < BK_NODES) {
        cnt[t] = 0;
        int node = b * BK_NODES + t;
        disl[t] = (node < N_NODES) ? dis[node] : 1.0f;
    }
    __syncthreads();
    int lo = bbase[b], hi = bbase[b + 1];
    for (int i = lo + t; i < hi; i += 256)
        atomicAdd(&cnt[ebkt[i] & (BK_NODES - 1)], 1);
    __syncthreads();
    int v = (t < BK_NODES) ? cnt[t] : 0;
    s[t] = v;
    __syncthreads();
    for (int off = 1; off < BK_NODES; off <<= 1) {
        int add = (t >= off) ? s[t - off] : 0;
        __syncthreads();
        s[t] += add;
        __syncthreads();
    }
    if (t < BK_NODES) cur[t] = s[t] - v;   // exclusive base within bucket
    __syncthreads();
    for (int i = lo + t; i < hi; i += 256) {
        unsigned int pk = ebkt[i];
        int cl = pk & (BK_NODES - 1);
        int r = pk >> BK_SHIFT;
        int slot = atomicAdd(&cur[cl], 1);
        float cf = dis[r] * disl[cl];
        edata[lo + slot] = make_int2(r, __float_as_int(cf));
    }
}

// ---------------- xw1 = x (N,128) @ W1 (128,64), output bf16 ----------------
__global__ __launch_bounds__(256) void k_xw1(const float* __restrict__ x,
                                             const float* __restrict__ W1,
                                             unsigned short* __restrict__ xw) {
    __shared__ float ws[F_INN * H1C];     // 32 KB
    __shared__ float xs[ROWS_PB * F_INN]; // 8 KB
    int tid = threadIdx.x;
    for (int i = tid; i < F_INN * H1C; i += 256) ws[i] = W1[i];
    int row0 = blockIdx.x * ROWS_PB;
    for (int i = tid; i < ROWS_PB * F_INN; i += 256) {
        int r = row0 + i / F_INN;
        xs[i] = (r < N_NODES) ? x[(size_t)r * F_INN + (i % F_INN)] : 0.0f;
    }
    __syncthreads();
    int c = tid & 63;
    int rb = tid >> 6;
    float acc[4] = {0.f, 0.f, 0.f, 0.f};
    for (int k = 0; k < F_INN; ++k) {
        float wv = ws[k * H1C + c];
#pragma unroll
        for (int i = 0; i < 4; ++i)
            acc[i] += xs[(rb + i * 4) * F_INN + k] * wv;
    }
#pragma unroll
    for (int i = 0; i < 4; ++i) {
        int r = row0 + rb + i * 4;
        if (r < N_NODES) xw[(size_t)r * H1C + c] = f2bf(acc[i]);
    }
}

// ------- conv1 gather-aggregate, bf16 rows (128B), 16 edges/iter, wave per node -------
__global__ __launch_bounds__(256) void k_agg1f(const int* __restrict__ rowptr,
                                               const int2* __restrict__ edata,
                                               const unsigned short* __restrict__ xwb,
                                               const float* __restrict__ dis,
                                               const float* __restrict__ b1,
                                               const float* __restrict__ W2,
                                               float* __restrict__ x1,
                                               float* __restrict__ xw2) {
    int wid = blockIdx.x * 4 + (threadIdx.x >> 6);
    int lane = threadIdx.x & 63;
    if (wid >= N_NODES) return;
    int grp = lane >> 4;      // 0..3
    int sub = lane & 15;      // 0..15
    int base = rowptr[wid], endp = rowptr[wid + 1];
    float4 acc = make_float4(0.f, 0.f, 0.f, 0.f);
    for (int e0 = base; e0 < endp; e0 += 16) {
        int2 ed[4];
#pragma unroll
        for (int q = 0; q < 4; ++q) {
            int idx = e0 + q * 4 + grp;
            ed[q] = (idx < endp) ? edata[idx] : make_int2(wid, 0);
        }
        uint2 qv[4];
#pragma unroll
        for (int q = 0; q < 4; ++q)
            qv[q] = ((const uint2*)(xwb + (size_t)ed[q].x * H1C))[sub];
#pragma unroll
        for (int q = 0; q < 4; ++q) {
            float cf = __int_as_float(ed[q].y);
            acc.x += bfl(qv[q].x) * cf;
            acc.y += bfh(qv[q].x) * cf;
            acc.z += bfl(qv[q].y) * cf;
            acc.w += bfh(qv[q].y) * cf;
        }
    }
    acc.x += __shfl_xor(acc.x, 16); acc.x += __shfl_xor(acc.x, 32);
    acc.y += __shfl_xor(acc.y, 16); acc.y += __shfl_xor(acc.y, 32);
    acc.z += __shfl_xor(acc.z, 16); acc.z += __shfl_xor(acc.z, 32);
    acc.w += __shfl_xor(acc.w, 16); acc.w += __shfl_xor(acc.w, 32);
    if (grp == 0) {
        float d = dis[wid];
        float d2 = d * d;
        uint2 ow = ((const uint2*)(xwb + (size_t)wid * H1C))[sub];
        float4 bb = ((const float4*)b1)[sub];
        float4 r;
        r.x = tanhf(acc.x + bfl(ow.x) * d2 + bb.x);
        r.y = tanhf(acc.y + bfh(ow.x) * d2 + bb.y);
        r.z = tanhf(acc.z + bfl(ow.y) * d2 + bb.z);
        r.w = tanhf(acc.w + bfh(ow.y) * d2 + bb.w);
        ((float4*)(x1 + (size_t)wid * H1C))[sub] = r;
        float4 w2v = ((const float4*)W2)[sub];
        float s = r.x * w2v.x + r.y * w2v.y + r.z * w2v.z + r.w * w2v.w;
        s += __shfl_xor(s, 8);
        s += __shfl_xor(s, 4);
        s += __shfl_xor(s, 2);
        s += __shfl_xor(s, 1);
        if (sub == 0) xw2[wid] = s;
    }
}

// ------- conv2 gather-aggregate (scalar) + tanh (wave per node) -------
__global__ __launch_bounds__(256) void k_agg2f(const int* __restrict__ rowptr,
                                               const int2* __restrict__ edata,
                                               const float* __restrict__ xw2,
                                               const float* __restrict__ dis,
                                               const float* __restrict__ b2,
                                               float* __restrict__ x2) {
    int wid = blockIdx.x * 4 + (threadIdx.x >> 6);
    int lane = threadIdx.x & 63;
    if (wid >= N_NODES) return;
    int base = rowptr[wid], endp = rowptr[wid + 1];
    float acc = 0.0f;
    for (int idx = base + lane; idx < endp; idx += 64) {
        int2 ed = edata[idx];
        acc += xw2[ed.x] * __int_as_float(ed.y);
    }
    for (int off = 32; off; off >>= 1) acc += __shfl_xor(acc, off);
    if (lane == 0) {
        float d = dis[wid];
        x2[wid] = tanhf(acc + xw2[wid] * d * d + b2[0]);
    }
}

// ------- sort-pool: wave per graph, scores register-resident (cap 512 >> ~200) -------
__global__ __launch_bounds__(256) void k_pool(const int* __restrict__ batch,
                                              const float* __restrict__ x1,
                                              const float* __restrict__ x2,
                                              float* __restrict__ p) {
    int g = blockIdx.x * 4 + (threadIdx.x >> 6);
    int lane = threadIdx.x & 63;
    if (g >= B_GRAPHS) return;
    int lo = 0, hi = N_NODES;
    while (lo < hi) { int m = (lo + hi) >> 1; if (batch[m] < g) lo = m + 1; else hi = m; }
    int start = lo;
    hi = N_NODES;
    while (lo < hi) { int m = (lo + hi) >> 1; if (batch[m] < g + 1) lo = m + 1; else hi = m; }
    int end = lo;
    int count = end - start;
    unsigned long long k[8];
#pragma unroll
    for (int i = 0; i < 8; ++i) {
        int idx = start + i * 64 + lane;
        unsigned long long key = 0ULL;
        if (idx < end) {
            unsigned int bits = __float_as_uint(x2[idx]);
            unsigned int u = (bits & 0x80000000u) ? ~bits : (bits | 0x80000000u);
            key = ((unsigned long long)u << 32) | (unsigned int)(~(unsigned int)idx);
        }
        k[i] = key;
    }
    int kk = count < K_TOP ? count : K_TOP;
    for (int j = 0; j < kk; ++j) {
        unsigned long long best = k[0];
#pragma unroll
        for (int i = 1; i < 8; ++i) if (k[i] > best) best = k[i];
#pragma unroll
        for (int off = 32; off; off >>= 1) {
            unsigned long long o = __shfl_xor(best, off);
            if (o > best) best = o;
        }
        int node = (int)(~(unsigned int)(best & 0xFFFFFFFFULL));
#pragma unroll
        for (int i = 0; i < 8; ++i) if (k[i] == best) k[i] = 0ULL;
        size_t off0 = (size_t)g * P_LEN + (size_t)j * XC;
        p[off0 + lane] = x1[(size_t)node * H1C + lane];
        if (lane == 0) p[off0 + 64] = x2[node];
    }
}

// ---------------- head ----------------
__global__ __launch_bounds__(256) void k_head(const float* __restrict__ p,
                                              const float* __restrict__ w3, const float* __restrict__ b3,
                                              const float* __restrict__ w4, const float* __restrict__ b4,
                                              const float* __restrict__ fw1, const float* __restrict__ fb1,
                                              const float* __restrict__ fw2, const float* __restrict__ fb2,
                                              float* __restrict__ out) {
    __shared__ float ps[P_LEN];
    __shared__ float h1s[C3_OUT * C3_L];
    __shared__ float h2s[C3_OUT * P2_L];
    __shared__ float h3s[FC1_IN];
    __shared__ float lls[FC1_OUT];
    __shared__ float outs[NUM_CLASSES];
    int g = blockIdx.x, tid = threadIdx.x;
    for (int i = tid; i < P_LEN; i += 256) ps[i] = p[(size_t)g * P_LEN + i];
    __syncthreads();
    for (int o = tid; o < C3_OUT * C3_L; o += 256) {
        int oc = o / C3_L, pos = o % C3_L;
        float s = b3[oc];
        const float* w = w3 + oc * C3_K;
        int base = pos * C3_K;
        for (int k = 0; k < C3_K; ++k) s += ps[base + k] * w[k];
        h1s[o] = fmaxf(s, 0.0f);
    }
    __syncthreads();
    if (tid < C3_OUT * P2_L) {
        int oc = tid / P2_L, pos = tid % P2_L;
        h2s[tid] = fmaxf(h1s[oc * C3_L + 2 * pos], h1s[oc * C3_L + 2 * pos + 1]);
    }
    __syncthreads();
    if (tid < C4_OUT * C4_L) {
        int oc = tid / C4_L, pos = tid % C4_L;
        float s = b4[oc];
        for (int ic = 0; ic < C3_OUT; ++ic)
#pragma unroll
            for (int k = 0; k < C4_K; ++k)
                s += h2s[ic * P2_L + pos + k] * w4[oc * C3_OUT * C4_K + ic * C4_K + k];
        h3s[oc * C4_L + pos] = fmaxf(s, 0.0f);
    }
    __syncthreads();
    if (tid < FC1_OUT) {
        float s = fb1[tid];
        for (int i = 0; i < FC1_IN; ++i) s += h3s[i] * fw1[i * FC1_OUT + tid];
        float v = fmaxf(s, 0.0f);
        lls[tid] = v;
        out[2 * B_GRAPHS * NUM_CLASSES + (size_t)g * FC1_OUT + tid] = v;
    }
    __syncthreads();
    if (tid < NUM_CLASSES) {
        float s = fb2[tid];
        for (int j = 0; j < FC1_OUT; ++j) s += lls[j] * fw2[j * NUM_CLASSES + tid];
        outs[tid] = s;
        out[B_GRAPHS * NUM_CLASSES + (size_t)g * NUM_CLASSES + tid] = s;
    }
    __syncthreads();
    if (tid < NUM_CLASSES) {
        float m = -INFINITY;
        for (int k2 = 0; k2 < NUM_CLASSES; ++k2) m = fmaxf(m, outs[k2]);
        float se = 0.0f;
        for (int k2 = 0; k2 < NUM_CLASSES; ++k2) se += expf(outs[k2] - m);
        out[(size_t)g * NUM_CLASSES + tid] = outs[tid] - m - logf(se);
    }
}

extern "C" void kernel_launch(void* const* d_in, const int* in_sizes, int n_in,
                              void* d_out, int out_size, void* d_ws, size_t ws_size,
                              hipStream_t stream) {
    const float* x   = (const float*)d_in[0];
    const int*   ei  = (const int*)d_in[1];
    const int*   row = ei;
    const int*   col = ei + N_EDGES;
    const int*   bat = (const int*)d_in[2];
    const float* W1  = (const float*)d_in[4];
    const float* b1  = (const float*)d_in[5];
    const float* W2  = (const float*)d_in[6];
    const float* b2  = (const float*)d_in[7];
    const float* w3  = (const float*)d_in[8];
    const float* b3  = (const float*)d_in[9];
    const float* w4  = (const float*)d_in[10];
    const float* b4  = (const float*)d_in[11];
    const float* fw1 = (const float*)d_in[12];
    const float* fb1 = (const float*)d_in[13];
    const float* fw2 = (const float*)d_in[14];
    const float* fb2 = (const float*)d_in[15];

    char* wsb = (char*)d_ws;
    unsigned short* xw1 = (unsigned short*)wsb;       wsb += (size_t)N_NODES * H1C * 2;  // 12.8 MB bf16
    float* x1     = (float*)wsb;                      wsb += (size_t)N_NODES * H1C * 4;  // 25.6 MB
    int2*  edata  = (int2*)wsb;                       wsb += (size_t)N_EDGES * 8;        // 25.6 MB
    // ebkt aliases x1: consumed by k_csrscatter before k_agg1f writes x1
    unsigned int* ebkt = (unsigned int*)x1;
    int*   bcount = (int*)wsb;                        wsb += (size_t)NBKT * 4;
    int*   bbase  = (int*)wsb;                        wsb += (size_t)(NBKT + 1) * 4;
    int*   gcur   = (int*)wsb;                        wsb += (size_t)NBKT * 4;
    int*   deg    = (int*)wsb;                        wsb += (size_t)N_NODES * 4;
    int*   rowptr = (int*)wsb;                        wsb += (size_t)(N_NODES + 1) * 4;
    float* dis    = (float*)wsb;                      wsb += (size_t)N_NODES * 4;
    float* xw2    = (float*)wsb;                      wsb += (size_t)N_NODES * 4;
    float* x2     = (float*)wsb;                      wsb += (size_t)N_NODES * 4;
    float* p      = (float*)wsb;                      wsb += (size_t)B_GRAPHS * P_LEN * 4;
    float* outp   = (float*)d_out;

    hipMemsetAsync(bcount, 0, (size_t)NBKT * 4, stream);
    hipMemsetAsync(p, 0, (size_t)B_GRAPHS * P_LEN * 4, stream);

    k_bcount<<<(N_EDGES + 2047) / 2048, 256, 0, stream>>>(row, col, bcount);
    k_bscan<<<1, 1024, 0, stream>>>(bcount, bbase, gcur);
    k_mscatter<<<(N_EDGES + MS_EPB - 1) / MS_EPB, 256, 0, stream>>>(row, col, gcur, ebkt);
    k_degtile<<<NBKT, 256, 0, stream>>>(ebkt, bbase, deg, rowptr);
    k_dis<<<(N_NODES + 255) / 256, 256, 0, stream>>>(deg, dis);
    k_csrscatter<<<NBKT, 256, 0, stream>>>(ebkt, bbase, dis, edata);
    k_xw1<<<(N_NODES + ROWS_PB - 1) / ROWS_PB, 256, 0, stream>>>(x, W1, xw1);
    k_agg1f<<<(N_NODES + 3) / 4, 256, 0, stream>>>(rowptr, edata, xw1, dis, b1, W2, x1, xw2);
    k_agg2f<<<(N_NODES + 3) / 4, 256, 0, stream>>>(rowptr, edata, xw2, dis, b2, x2);
    k_pool<<<(B_GRAPHS + 3) / 4, 256, 0, stream>>>(bat, x1, x2, p);
    k_head<<<B_GRAPHS, 256, 0, stream>>>(p, w3, b3, w4, b4, fw1, fb1, fw2, fb2, outp);
}

// Round 7
// 406.132 us; speedup vs baseline: 3.4189x; 1.1886x over previous
//
#include <hip/hip_runtime.h>
#include <math.h>

#define N_NODES 100000
#define N_EDGES 3200000
#define B_GRAPHS 500
#define K_TOP 30
#define F_INN 128
#define H1C 64
#define NUM_CLASSES 18
#define XC 65               // H1 + 1
#define P_LEN (K_TOP * XC)  // 1950
#define C3_OUT 16
#define C3_K 97
#define C3_L 20
#define P2_L 10
#define C4_OUT 32
#define C4_K 5
#define C4_L 6
#define FC1_IN 192
#define FC1_OUT 128
#define ROWS_PB 16

#define BK_SHIFT 7
#define BK_NODES 128                               // nodes per bucket
#define NBKT ((N_NODES + BK_NODES - 1) / BK_NODES) // 782
#define BSTRIDE 5120                               // slots per bucket (mean 4092 + 16 sigma)
#define MS_EPT 16                                  // edges per thread in mscatter
#define MS_EPB (256 * MS_EPT)                      // 4096 edges per block

// bf16 helpers
static __device__ __forceinline__ unsigned short f2bf(float f) {
    unsigned int u = __float_as_uint(f);
    u += 0x7FFFu + ((u >> 16) & 1u);   // round to nearest even
    return (unsigned short)(u >> 16);
}
static __device__ __forceinline__ float bfl(unsigned int u) {   // low bf16
    return __uint_as_float(u << 16);
}
static __device__ __forceinline__ float bfh(unsigned int u) {   // high bf16
    return __uint_as_float(u & 0xFFFF0000u);
}

// ------- multi-split scatter: ebkt[b*BSTRIDE + slot] = (row<<7 | col_local) -------
__global__ __launch_bounds__(256) void k_mscatter(const int* __restrict__ row,
                                                  const int* __restrict__ col,
                                                  int* __restrict__ gcur,
                                                  unsigned int* __restrict__ ebkt) {
    __shared__ int hist[NBKT];
    __shared__ int base[NBKT];
    int tid = threadIdx.x;
    for (int i = tid; i < NBKT; i += 256) hist[i] = 0;
    __syncthreads();
    unsigned int pk[MS_EPT];   // (bucket<<12) | rank, or sentinel
    unsigned int pay[MS_EPT];  // (row<<7) | col_local
    int e0 = blockIdx.x * MS_EPB;
#pragma unroll
    for (int j = 0; j < MS_EPT; ++j) {
        int e = e0 + j * 256 + tid;
        pk[j] = 0xFFFFFFFFu;
        if (e < N_EDGES) {
            int r = row[e], c = col[e];
            if (r != c) {
                int b = c >> BK_SHIFT;
                int rank = atomicAdd(&hist[b], 1);
                pk[j] = ((unsigned int)b << 12) | (unsigned int)rank;
                pay[j] = ((unsigned int)r << BK_SHIFT) | (unsigned int)(c & (BK_NODES - 1));
            }
        }
    }
    __syncthreads();
    for (int i = tid; i < NBKT; i += 256)
        base[i] = hist[i] ? (i * BSTRIDE + atomicAdd(&gcur[i], hist[i])) : 0;
    __syncthreads();
#pragma unroll
    for (int j = 0; j < MS_EPT; ++j) {
        if (pk[j] != 0xFFFFFFFFu) {
            int b = pk[j] >> 12;
            int rank = pk[j] & 0xFFF;
            ebkt[base[b] + rank] = pay[j];
        }
    }
}

// ------- merged CSR build: count -> scan -> dis/rowse -> rank-scatter erow -------
__global__ __launch_bounds__(256) void k_csr(const unsigned int* __restrict__ ebkt,
                                             const int* __restrict__ gcur,
                                             float* __restrict__ dis,
                                             int2* __restrict__ rowse,
                                             int* __restrict__ erow) {
    __shared__ int cnt[BK_NODES];
    __shared__ int s[256];
    __shared__ int cur[BK_NODES];
    int b = blockIdx.x, t = threadIdx.x;
    if (t < BK_NODES) cnt[t] = 0;
    __syncthreads();
    int lo = b * BSTRIDE;
    int hi = lo + gcur[b];
    for (int i = lo + t; i < hi; i += 256)
        atomicAdd(&cnt[ebkt[i] & (BK_NODES - 1)], 1);
    __syncthreads();
    int v = (t < BK_NODES) ? cnt[t] : 0;
    s[t] = v;
    __syncthreads();
    for (int off = 1; off < BK_NODES; off <<= 1) {
        int add = (t >= off) ? s[t - off] : 0;
        __syncthreads();
        s[t] += add;
        __syncthreads();
    }
    int ex = s[t] - v;
    if (t < BK_NODES) {
        int node = b * BK_NODES + t;
        if (node < N_NODES) {
            dis[node] = rsqrtf((float)v + 1.0f);
            rowse[node] = make_int2(lo + ex, lo + ex + v);
        }
        cur[t] = lo + ex;
    }
    __syncthreads();
    for (int i = lo + t; i < hi; i += 256) {
        unsigned int pk = ebkt[i];
        int cl = pk & (BK_NODES - 1);
        int slot = atomicAdd(&cur[cl], 1);
        erow[slot] = (int)(pk >> BK_SHIFT);
    }
}

// ---------------- xws = dis[r] * (x @ W1), bf16 output ----------------
__global__ __launch_bounds__(256) void k_xw1(const float* __restrict__ x,
                                             const float* __restrict__ W1,
                                             const float* __restrict__ dis,
                                             unsigned short* __restrict__ xw) {
    __shared__ float ws[F_INN * H1C];     // 32 KB
    __shared__ float xs[ROWS_PB * F_INN]; // 8 KB
    int tid = threadIdx.x;
    for (int i = tid; i < F_INN * H1C; i += 256) ws[i] = W1[i];
    int row0 = blockIdx.x * ROWS_PB;
    for (int i = tid; i < ROWS_PB * F_INN; i += 256) {
        int r = row0 + i / F_INN;
        xs[i] = (r < N_NODES) ? x[(size_t)r * F_INN + (i % F_INN)] : 0.0f;
    }
    __syncthreads();
    int c = tid & 63;
    int rb = tid >> 6;
    float acc[4] = {0.f, 0.f, 0.f, 0.f};
    for (int k = 0; k < F_INN; ++k) {
        float wv = ws[k * H1C + c];
#pragma unroll
        for (int i = 0; i < 4; ++i)
            acc[i] += xs[(rb + i * 4) * F_INN + k] * wv;
    }
#pragma unroll
    for (int i = 0; i < 4; ++i) {
        int r = row0 + rb + i * 4;
        if (r < N_NODES) xw[(size_t)r * H1C + c] = f2bf(acc[i] * dis[r]);
    }
}

// ------- conv1 gather: 8 lanes/edge, uint4 bf16, pure add; wave per node -------
__global__ __launch_bounds__(256) void k_agg1f(const int2* __restrict__ rowse,
                                               const int* __restrict__ erow,
                                               const unsigned short* __restrict__ xws,
                                               const float* __restrict__ dis,
                                               const float* __restrict__ b1,
                                               const float* __restrict__ W2,
                                               float* __restrict__ x1,
                                               float* __restrict__ xws2) {
    int wid = blockIdx.x * 4 + (threadIdx.x >> 6);
    int lane = threadIdx.x & 63;
    if (wid >= N_NODES) return;
    int grp = lane >> 3;   // 0..7
    int sub = lane & 7;    // 0..7
    int2 se = rowse[wid];
    int base = se.x, endp = se.y;
    float acc[8] = {0.f, 0.f, 0.f, 0.f, 0.f, 0.f, 0.f, 0.f};
    for (int e0 = base; e0 < endp; e0 += 16) {
        int i0 = e0 + grp;
        int i1 = e0 + 8 + grp;
        int r0 = (i0 < endp) ? erow[i0] : N_NODES;   // row N_NODES is all-zero
        int r1 = (i1 < endp) ? erow[i1] : N_NODES;
        uint4 a = ((const uint4*)(xws + (size_t)r0 * H1C))[sub];
        uint4 bq = ((const uint4*)(xws + (size_t)r1 * H1C))[sub];
        acc[0] += bfl(a.x) + bfl(bq.x);
        acc[1] += bfh(a.x) + bfh(bq.x);
        acc[2] += bfl(a.y) + bfl(bq.y);
        acc[3] += bfh(a.y) + bfh(bq.y);
        acc[4] += bfl(a.z) + bfl(bq.z);
        acc[5] += bfh(a.z) + bfh(bq.z);
        acc[6] += bfl(a.w) + bfl(bq.w);
        acc[7] += bfh(a.w) + bfh(bq.w);
    }
#pragma unroll
    for (int i = 0; i < 8; ++i) {
        acc[i] += __shfl_xor(acc[i], 8);
        acc[i] += __shfl_xor(acc[i], 16);
        acc[i] += __shfl_xor(acc[i], 32);
    }
    if (grp == 0) {   // lanes 0..7 hold channels [8*sub, 8*sub+8)
        float d = dis[wid];
        uint4 ow = ((const uint4*)(xws + (size_t)wid * H1C))[sub];
        float self[8] = {bfl(ow.x), bfh(ow.x), bfl(ow.y), bfh(ow.y),
                         bfl(ow.z), bfh(ow.z), bfl(ow.w), bfh(ow.w)};
        float4 bb0 = ((const float4*)b1)[sub * 2];
        float4 bb1 = ((const float4*)b1)[sub * 2 + 1];
        float r[8];
        r[0] = tanhf(d * (acc[0] + self[0]) + bb0.x);
        r[1] = tanhf(d * (acc[1] + self[1]) + bb0.y);
        r[2] = tanhf(d * (acc[2] + self[2]) + bb0.z);
        r[3] = tanhf(d * (acc[3] + self[3]) + bb0.w);
        r[4] = tanhf(d * (acc[4] + self[4]) + bb1.x);
        r[5] = tanhf(d * (acc[5] + self[5]) + bb1.y);
        r[6] = tanhf(d * (acc[6] + self[6]) + bb1.z);
        r[7] = tanhf(d * (acc[7] + self[7]) + bb1.w);
        ((float4*)(x1 + (size_t)wid * H1C))[sub * 2] = make_float4(r[0], r[1], r[2], r[3]);
        ((float4*)(x1 + (size_t)wid * H1C))[sub * 2 + 1] = make_float4(r[4], r[5], r[6], r[7]);
        float4 w20 = ((const float4*)W2)[sub * 2];
        float4 w21 = ((const float4*)W2)[sub * 2 + 1];
        float s = r[0] * w20.x + r[1] * w20.y + r[2] * w20.z + r[3] * w20.w +
                  r[4] * w21.x + r[5] * w21.y + r[6] * w21.z + r[7] * w21.w;
        s += __shfl_xor(s, 1);
        s += __shfl_xor(s, 2);
        s += __shfl_xor(s, 4);
        if (sub == 0) xws2[wid] = d * s;   // pre-scaled by dis
    }
}

// ------- conv2 gather (scalar, pre-scaled) + tanh (wave per node) -------
__global__ __launch_bounds__(256) void k_agg2f(const int2* __restrict__ rowse,
                                               const int* __restrict__ erow,
                                               const float* __restrict__ xws2,
                                               const float* __restrict__ dis,
                                               const float* __restrict__ b2,
                                               float* __restrict__ x2) {
    int wid = blockIdx.x * 4 + (threadIdx.x >> 6);
    int lane = threadIdx.x & 63;
    if (wid >= N_NODES) return;
    int2 se = rowse[wid];
    float acc = 0.0f;
    for (int idx = se.x + lane; idx < se.y; idx += 64)
        acc += xws2[erow[idx]];
    for (int off = 32; off; off >>= 1) acc += __shfl_xor(acc, off);
    if (lane == 0)
        x2[wid] = tanhf(dis[wid] * (acc + xws2[wid]) + b2[0]);
}

// ------- sort-pool: wave per graph, scores register-resident (cap 512 >> ~200) -------
__global__ __launch_bounds__(256) void k_pool(const int* __restrict__ batch,
                                              const float* __restrict__ x1,
                                              const float* __restrict__ x2,
                                              float* __restrict__ p) {
    int g = blockIdx.x * 4 + (threadIdx.x >> 6);
    int lane = threadIdx.x & 63;
    if (g >= B_GRAPHS) return;
    int lo = 0, hi = N_NODES;
    while (lo < hi) { int m = (lo + hi) >> 1; if (batch[m] < g) lo = m + 1; else hi = m; }
    int start = lo;
    hi = N_NODES;
    while (lo < hi) { int m = (lo + hi) >> 1; if (batch[m] < g + 1) lo = m + 1; else hi = m; }
    int end = lo;
    int count = end - start;
    unsigned long long k[8];
#pragma unroll
    for (int i = 0; i < 8; ++i) {
        int idx = start + i * 64 + lane;
        unsigned long long key = 0ULL;
        if (idx < end) {
            unsigned int bits = __float_as_uint(x2[idx]);
            unsigned int u = (bits & 0x80000000u) ? ~bits : (bits | 0x80000000u);
            key = ((unsigned long long)u << 32) | (unsigned int)(~(unsigned int)idx);
        }
        k[i] = key;
    }
    int kk = count < K_TOP ? count : K_TOP;
    for (int j = 0; j < kk; ++j) {
        unsigned long long best = k[0];
#pragma unroll
        for (int i = 1; i < 8; ++i) if (k[i] > best) best = k[i];
#pragma unroll
        for (int off = 32; off; off >>= 1) {
            unsigned long long o = __shfl_xor(best, off);
            if (o > best) best = o;
        }
        int node = (int)(~(unsigned int)(best & 0xFFFFFFFFULL));
#pragma unroll
        for (int i = 0; i < 8; ++i) if (k[i] == best) k[i] = 0ULL;
        size_t off0 = (size_t)g * P_LEN + (size_t)j * XC;
        p[off0 + lane] = x1[(size_t)node * H1C + lane];
        if (lane == 0) p[off0 + 64] = x2[node];
    }
}

// ---------------- head ----------------
__global__ __launch_bounds__(256) void k_head(const float* __restrict__ p,
                                              const float* __restrict__ w3, const float* __restrict__ b3,
                                              const float* __restrict__ w4, const float* __restrict__ b4,
                                              const float* __restrict__ fw1, const float* __restrict__ fb1,
                                              const float* __restrict__ fw2, const float* __restrict__ fb2,
                                              float* __restrict__ out) {
    __shared__ float ps[P_LEN];
    __shared__ float h1s[C3_OUT * C3_L];
    __shared__ float h2s[C3_OUT * P2_L];
    __shared__ float h3s[FC1_IN];
    __shared__ float lls[FC1_OUT];
    __shared__ float outs[NUM_CLASSES];
    int g = blockIdx.x, tid = threadIdx.x;
    for (int i = tid; i < P_LEN; i += 256) ps[i] = p[(size_t)g * P_LEN + i];
    __syncthreads();
    for (int o = tid; o < C3_OUT * C3_L; o += 256) {
        int oc = o / C3_L, pos = o % C3_L;
        float s = b3[oc];
        const float* w = w3 + oc * C3_K;
        int base = pos * C3_K;
        for (int k = 0; k < C3_K; ++k) s += ps[base + k] * w[k];
        h1s[o] = fmaxf(s, 0.0f);
    }
    __syncthreads();
    if (tid < C3_OUT * P2_L) {
        int oc = tid / P2_L, pos = tid % P2_L;
        h2s[tid] = fmaxf(h1s[oc * C3_L + 2 * pos], h1s[oc * C3_L + 2 * pos + 1]);
    }
    __syncthreads();
    if (tid < C4_OUT * C4_L) {
        int oc = tid / C4_L, pos = tid % C4_L;
        float s = b4[oc];
        for (int ic = 0; ic < C3_OUT; ++ic)
#pragma unroll
            for (int k = 0; k < C4_K; ++k)
                s += h2s[ic * P2_L + pos + k] * w4[oc * C3_OUT * C4_K + ic * C4_K + k];
        h3s[oc * C4_L + pos] = fmaxf(s, 0.0f);
    }
    __syncthreads();
    if (tid < FC1_OUT) {
        float s = fb1[tid];
        for (int i = 0; i < FC1_IN; ++i) s += h3s[i] * fw1[i * FC1_OUT + tid];
        float v = fmaxf(s, 0.0f);
        lls[tid] = v;
        out[2 * B_GRAPHS * NUM_CLASSES + (size_t)g * FC1_OUT + tid] = v;
    }
    __syncthreads();
    if (tid < NUM_CLASSES) {
        float s = fb2[tid];
        for (int j = 0; j < FC1_OUT; ++j) s += lls[j] * fw2[j * NUM_CLASSES + tid];
        outs[tid] = s;
        out[B_GRAPHS * NUM_CLASSES + (size_t)g * NUM_CLASSES + tid] = s;
    }
    __syncthreads();
    if (tid < NUM_CLASSES) {
        float m = -INFINITY;
        for (int k2 = 0; k2 < NUM_CLASSES; ++k2) m = fmaxf(m, outs[k2]);
        float se = 0.0f;
        for (int k2 = 0; k2 < NUM_CLASSES; ++k2) se += expf(outs[k2] - m);
        out[(size_t)g * NUM_CLASSES + tid] = outs[tid] - m - logf(se);
    }
}

extern "C" void kernel_launch(void* const* d_in, const int* in_sizes, int n_in,
                              void* d_out, int out_size, void* d_ws, size_t ws_size,
                              hipStream_t stream) {
    const float* x   = (const float*)d_in[0];
    const int*   ei  = (const int*)d_in[1];
    const int*   row = ei;
    const int*   col = ei + N_EDGES;
    const int*   bat = (const int*)d_in[2];
    const float* W1  = (const float*)d_in[4];
    const float* b1  = (const float*)d_in[5];
    const float* W2  = (const float*)d_in[6];
    const float* b2  = (const float*)d_in[7];
    const float* w3  = (const float*)d_in[8];
    const float* b3  = (const float*)d_in[9];
    const float* w4  = (const float*)d_in[10];
    const float* b4  = (const float*)d_in[11];
    const float* fw1 = (const float*)d_in[12];
    const float* fb1 = (const float*)d_in[13];
    const float* fw2 = (const float*)d_in[14];
    const float* fb2 = (const float*)d_in[15];

    char* wsb = (char*)d_ws;
    unsigned short* xws = (unsigned short*)wsb;       wsb += (size_t)(N_NODES + 1) * H1C * 2; // 12.8 MB (+zero row)
    float* x1     = (float*)wsb;                      wsb += (size_t)N_NODES * H1C * 4;       // 25.6 MB
    int*   erow   = (int*)wsb;                        wsb += (size_t)NBKT * BSTRIDE * 4;      // 16.0 MB
    // ebkt aliases x1 (16.0 MB <= 25.6 MB): consumed by k_csr before k_agg1f writes x1
    unsigned int* ebkt = (unsigned int*)x1;
    int*   gcur   = (int*)wsb;                        wsb += (size_t)NBKT * 4;
    int2*  rowse  = (int2*)wsb;                       wsb += (size_t)N_NODES * 8;
    float* dis    = (float*)wsb;                      wsb += (size_t)N_NODES * 4;
    float* xws2   = (float*)wsb;                      wsb += (size_t)N_NODES * 4;
    float* x2     = (float*)wsb;                      wsb += (size_t)N_NODES * 4;
    float* p      = (float*)wsb;                      wsb += (size_t)B_GRAPHS * P_LEN * 4;
    float* outp   = (float*)d_out;

    hipMemsetAsync(gcur, 0, (size_t)NBKT * 4, stream);
    hipMemsetAsync(p, 0, (size_t)B_GRAPHS * P_LEN * 4, stream);
    hipMemsetAsync(xws + (size_t)N_NODES * H1C, 0, H1C * 2, stream);  // zero row for padding

    k_mscatter<<<(N_EDGES + MS_EPB - 1) / MS_EPB, 256, 0, stream>>>(row, col, gcur, ebkt);
    k_csr<<<NBKT, 256, 0, stream>>>(ebkt, gcur, dis, rowse, erow);
    k_xw1<<<(N_NODES + ROWS_PB - 1) / ROWS_PB, 256, 0, stream>>>(x, W1, dis, xws);
    k_agg1f<<<(N_NODES + 3) / 4, 256, 0, stream>>>(rowse, erow, xws, dis, b1, W2, x1, xws2);
    k_agg2f<<<(N_NODES + 3) / 4, 256, 0, stream>>>(rowse, erow, xws2, dis, b2, x2);
    k_pool<<<(B_GRAPHS + 3) / 4, 256, 0, stream>>>(bat, x1, x2, p);
    k_head<<<B_GRAPHS, 256, 0, stream>>>(p, w3, b3, w4, b4, fw1, fb1, fw2, fb2, outp);
}

// Round 8
// 368.254 us; speedup vs baseline: 3.7706x; 1.1029x over previous
//
#include <hip/hip_runtime.h>
#include <math.h>

#define N_NODES 100000
#define N_EDGES 3200000
#define B_GRAPHS 500
#define K_TOP 30
#define F_INN 128
#define H1C 64
#define NUM_CLASSES 18
#define XC 65               // H1 + 1
#define P_LEN (K_TOP * XC)  // 1950
#define C3_OUT 16
#define C3_K 97
#define C3_L 20
#define P2_L 10
#define C4_OUT 32
#define C4_K 5
#define C4_L 6
#define FC1_IN 192
#define FC1_OUT 128

#define BK_SHIFT 7
#define BK_NODES 128                               // nodes per bucket
#define NBKT ((N_NODES + BK_NODES - 1) / BK_NODES) // 782
#define BSTRIDE 5120                               // slots per bucket (mean 4092 + 16 sigma)
#define MS_EPT 16                                  // edges per thread in mscatter
#define MS_EPB (256 * MS_EPT)                      // 4096 edges per block

typedef __attribute__((ext_vector_type(8))) short bf16x8;
typedef __attribute__((ext_vector_type(4))) float f32x4;

// bf16 helpers
static __device__ __forceinline__ unsigned short f2bf(float f) {
    unsigned int u = __float_as_uint(f);
    u += 0x7FFFu + ((u >> 16) & 1u);   // round to nearest even
    return (unsigned short)(u >> 16);
}
static __device__ __forceinline__ float bfl(unsigned int u) {   // low bf16
    return __uint_as_float(u << 16);
}
static __device__ __forceinline__ float bfh(unsigned int u) {   // high bf16
    return __uint_as_float(u & 0xFFFF0000u);
}

// ------- multi-split scatter: ebkt[b*BSTRIDE + slot] = (row<<7 | col_local) -------
__global__ __launch_bounds__(256) void k_mscatter(const int* __restrict__ row,
                                                  const int* __restrict__ col,
                                                  int* __restrict__ gcur,
                                                  unsigned int* __restrict__ ebkt) {
    __shared__ int hist[NBKT];
    __shared__ int base[NBKT];
    int tid = threadIdx.x;
    for (int i = tid; i < NBKT; i += 256) hist[i] = 0;
    __syncthreads();
    unsigned int pk[MS_EPT];   // (bucket<<12) | rank, or sentinel
    unsigned int pay[MS_EPT];  // (row<<7) | col_local
    int e0 = blockIdx.x * MS_EPB;
#pragma unroll
    for (int j = 0; j < MS_EPT; ++j) {
        int e = e0 + j * 256 + tid;
        pk[j] = 0xFFFFFFFFu;
        if (e < N_EDGES) {
            int r = row[e], c = col[e];
            if (r != c) {
                int b = c >> BK_SHIFT;
                int rank = atomicAdd(&hist[b], 1);
                pk[j] = ((unsigned int)b << 12) | (unsigned int)rank;
                pay[j] = ((unsigned int)r << BK_SHIFT) | (unsigned int)(c & (BK_NODES - 1));
            }
        }
    }
    __syncthreads();
    for (int i = tid; i < NBKT; i += 256)
        base[i] = hist[i] ? (i * BSTRIDE + atomicAdd(&gcur[i], hist[i])) : 0;
    __syncthreads();
#pragma unroll
    for (int j = 0; j < MS_EPT; ++j) {
        if (pk[j] != 0xFFFFFFFFu) {
            int b = pk[j] >> 12;
            int rank = pk[j] & 0xFFF;
            ebkt[base[b] + rank] = pay[j];
        }
    }
}

// ------- merged CSR build: count -> scan -> dis/rowse -> rank-scatter erow (byte offsets) -------
__global__ __launch_bounds__(256) void k_csr(const unsigned int* __restrict__ ebkt,
                                             const int* __restrict__ gcur,
                                             float* __restrict__ dis,
                                             int2* __restrict__ rowse,
                                             int* __restrict__ erow) {
    __shared__ int cnt[BK_NODES];
    __shared__ int s[256];
    __shared__ int cur[BK_NODES];
    int b = blockIdx.x, t = threadIdx.x;
    if (t < BK_NODES) cnt[t] = 0;
    __syncthreads();
    int lo = b * BSTRIDE;
    int hi = lo + gcur[b];
    for (int i = lo + t; i < hi; i += 256)
        atomicAdd(&cnt[ebkt[i] & (BK_NODES - 1)], 1);
    __syncthreads();
    int v = (t < BK_NODES) ? cnt[t] : 0;
    s[t] = v;
    __syncthreads();
    for (int off = 1; off < BK_NODES; off <<= 1) {
        int add = (t >= off) ? s[t - off] : 0;
        __syncthreads();
        s[t] += add;
        __syncthreads();
    }
    int ex = s[t] - v;
    if (t < BK_NODES) {
        int node = b * BK_NODES + t;
        if (node < N_NODES) {
            dis[node] = rsqrtf((float)v + 1.0f);
            rowse[node] = make_int2(lo + ex, lo + ex + v);
        }
        cur[t] = lo + ex;
    }
    __syncthreads();
    for (int i = lo + t; i < hi; i += 256) {
        unsigned int pk = ebkt[i];
        int cl = pk & (BK_NODES - 1);
        int slot = atomicAdd(&cur[cl], 1);
        erow[slot] = (int)((pk >> BK_SHIFT) << 7);   // byte offset into bf16 rows (128B)
    }
}

// ---------------- xws = dis[r] * (x @ W1) via MFMA, bf16 output ----------------
// block: 4 waves x 16 rows = 64 rows. W1 staged to LDS in B-fragment order (bf16).
__global__ __launch_bounds__(256) void k_xw1(const float* __restrict__ x,
                                             const float* __restrict__ W1,
                                             const float* __restrict__ dis,
                                             unsigned short* __restrict__ xw) {
    __shared__ unsigned short w1s[16 * 64 * 8];   // 16 frags x 64 lanes x 8 bf16 = 16KB
    int tid = threadIdx.x;
    // stage W1 (128x64 fp32) -> bf16 fragments: frag f=(kq*4+t), lane l, elem j
    // holds W1[kq*32 + (l>>4)*8 + j][t*16 + (l&15)]
    for (int idx = tid; idx < 16 * 64 * 8; idx += 256) {
        int f = idx >> 9;
        int l = (idx >> 3) & 63;
        int j = idx & 7;
        int kq = f >> 2, t4 = f & 3;
        int k = kq * 32 + ((l >> 4) << 3) + j;
        int n = t4 * 16 + (l & 15);
        w1s[idx] = f2bf(W1[k * H1C + n]);
    }
    __syncthreads();
    int wave = tid >> 6;
    int lane = tid & 63;
    int quad = lane >> 4;
    int m = lane & 15;
    int wrow0 = blockIdx.x * 64 + wave * 16;

    bf16x8 bw[16];
#pragma unroll
    for (int f = 0; f < 16; ++f)
        bw[f] = *(const bf16x8*)&w1s[(f * 64 + lane) * 8];

    f32x4 acc[4];
#pragma unroll
    for (int t = 0; t < 4; ++t) acc[t] = (f32x4){0.f, 0.f, 0.f, 0.f};

    int rowA = wrow0 + m;
    size_t ra = (size_t)(rowA < N_NODES ? rowA : N_NODES - 1);
#pragma unroll
    for (int kq = 0; kq < 4; ++kq) {
        const float* xp = x + ra * F_INN + kq * 32 + quad * 8;
        float4 f0 = ((const float4*)xp)[0];
        float4 f1 = ((const float4*)xp)[1];
        bf16x8 a;
        a[0] = (short)f2bf(f0.x); a[1] = (short)f2bf(f0.y);
        a[2] = (short)f2bf(f0.z); a[3] = (short)f2bf(f0.w);
        a[4] = (short)f2bf(f1.x); a[5] = (short)f2bf(f1.y);
        a[6] = (short)f2bf(f1.z); a[7] = (short)f2bf(f1.w);
#pragma unroll
        for (int t = 0; t < 4; ++t)
            acc[t] = __builtin_amdgcn_mfma_f32_16x16x32_bf16(a, bw[kq * 4 + t], acc[t], 0, 0, 0);
    }
#pragma unroll
    for (int r = 0; r < 4; ++r) {
        int rowD = wrow0 + quad * 4 + r;
        if (rowD < N_NODES) {
            float dsc = dis[rowD];
#pragma unroll
            for (int t = 0; t < 4; ++t)
                xw[(size_t)rowD * H1C + t * 16 + m] = f2bf(acc[t][r] * dsc);
        }
    }
}

// ------- conv1 gather: 8 lanes/edge, uint4 bf16, pure add; wave per node -------
__global__ __launch_bounds__(256) void k_agg1f(const int2* __restrict__ rowse,
                                               const int* __restrict__ erow,
                                               const unsigned short* __restrict__ xws,
                                               const float* __restrict__ dis,
                                               const float* __restrict__ b1,
                                               const float* __restrict__ W2,
                                               float* __restrict__ x1,
                                               float* __restrict__ xws2) {
    int wid = blockIdx.x * 4 + (threadIdx.x >> 6);
    int lane = threadIdx.x & 63;
    if (wid >= N_NODES) return;
    int grp = lane >> 3;   // 0..7
    int sub = lane & 7;    // 0..7
    int2 se = rowse[wid];
    int base = se.x, endp = se.y;
    const char* xb = (const char*)xws;
    float acc[8] = {0.f, 0.f, 0.f, 0.f, 0.f, 0.f, 0.f, 0.f};
    for (int e0 = base; e0 < endp; e0 += 16) {
        int i0 = e0 + grp;
        int i1 = e0 + 8 + grp;
        int o0 = (i0 < endp) ? erow[i0] : (N_NODES << 7);   // zero row pad
        int o1 = (i1 < endp) ? erow[i1] : (N_NODES << 7);
        uint4 a = ((const uint4*)(xb + o0))[sub];
        uint4 bq = ((const uint4*)(xb + o1))[sub];
        acc[0] += bfl(a.x) + bfl(bq.x);
        acc[1] += bfh(a.x) + bfh(bq.x);
        acc[2] += bfl(a.y) + bfl(bq.y);
        acc[3] += bfh(a.y) + bfh(bq.y);
        acc[4] += bfl(a.z) + bfl(bq.z);
        acc[5] += bfh(a.z) + bfh(bq.z);
        acc[6] += bfl(a.w) + bfl(bq.w);
        acc[7] += bfh(a.w) + bfh(bq.w);
    }
#pragma unroll
    for (int i = 0; i < 8; ++i) {
        acc[i] += __shfl_xor(acc[i], 8);
        acc[i] += __shfl_xor(acc[i], 16);
        acc[i] += __shfl_xor(acc[i], 32);
    }
    if (grp == 0) {   // lanes 0..7 hold channels [8*sub, 8*sub+8)
        float d = dis[wid];
        uint4 ow = ((const uint4*)(xb + ((size_t)wid << 7)))[sub];
        float self[8] = {bfl(ow.x), bfh(ow.x), bfl(ow.y), bfh(ow.y),
                         bfl(ow.z), bfh(ow.z), bfl(ow.w), bfh(ow.w)};
        float4 bb0 = ((const float4*)b1)[sub * 2];
        float4 bb1 = ((const float4*)b1)[sub * 2 + 1];
        float r[8];
        r[0] = tanhf(d * (acc[0] + self[0]) + bb0.x);
        r[1] = tanhf(d * (acc[1] + self[1]) + bb0.y);
        r[2] = tanhf(d * (acc[2] + self[2]) + bb0.z);
        r[3] = tanhf(d * (acc[3] + self[3]) + bb0.w);
        r[4] = tanhf(d * (acc[4] + self[4]) + bb1.x);
        r[5] = tanhf(d * (acc[5] + self[5]) + bb1.y);
        r[6] = tanhf(d * (acc[6] + self[6]) + bb1.z);
        r[7] = tanhf(d * (acc[7] + self[7]) + bb1.w);
        ((float4*)(x1 + (size_t)wid * H1C))[sub * 2] = make_float4(r[0], r[1], r[2], r[3]);
        ((float4*)(x1 + (size_t)wid * H1C))[sub * 2 + 1] = make_float4(r[4], r[5], r[6], r[7]);
        float4 w20 = ((const float4*)W2)[sub * 2];
        float4 w21 = ((const float4*)W2)[sub * 2 + 1];
        float s = r[0] * w20.x + r[1] * w20.y + r[2] * w20.z + r[3] * w20.w +
                  r[4] * w21.x + r[5] * w21.y + r[6] * w21.z + r[7] * w21.w;
        s += __shfl_xor(s, 1);
        s += __shfl_xor(s, 2);
        s += __shfl_xor(s, 4);
        if (sub == 0) xws2[wid] = d * s;   // pre-scaled by dis
    }
}

// ------- conv2 gather (scalar, pre-scaled) + tanh (wave per node) -------
__global__ __launch_bounds__(256) void k_agg2f(const int2* __restrict__ rowse,
                                               const int* __restrict__ erow,
                                               const float* __restrict__ xws2,
                                               const float* __restrict__ dis,
                                               const float* __restrict__ b2,
                                               float* __restrict__ x2) {
    int wid = blockIdx.x * 4 + (threadIdx.x >> 6);
    int lane = threadIdx.x & 63;
    if (wid >= N_NODES) return;
    int2 se = rowse[wid];
    float acc = 0.0f;
    for (int idx = se.x + lane; idx < se.y; idx += 64)
        acc += xws2[erow[idx] >> 7];
    for (int off = 32; off; off >>= 1) acc += __shfl_xor(acc, off);
    if (lane == 0)
        x2[wid] = tanhf(dis[wid] * (acc + xws2[wid]) + b2[0]);
}

// ------- sort-pool: wave per graph, scores register-resident (cap 512 >> ~200) -------
__global__ __launch_bounds__(256) void k_pool(const int* __restrict__ batch,
                                              const float* __restrict__ x1,
                                              const float* __restrict__ x2,
                                              float* __restrict__ p) {
    int g = blockIdx.x * 4 + (threadIdx.x >> 6);
    int lane = threadIdx.x & 63;
    if (g >= B_GRAPHS) return;
    int lo = 0, hi = N_NODES;
    while (lo < hi) { int m = (lo + hi) >> 1; if (batch[m] < g) lo = m + 1; else hi = m; }
    int start = lo;
    hi = N_NODES;
    while (lo < hi) { int m = (lo + hi) >> 1; if (batch[m] < g + 1) lo = m + 1; else hi = m; }
    int end = lo;
    int count = end - start;
    unsigned long long k[8];
#pragma unroll
    for (int i = 0; i < 8; ++i) {
        int idx = start + i * 64 + lane;
        unsigned long long key = 0ULL;
        if (idx < end) {
            unsigned int bits = __float_as_uint(x2[idx]);
            unsigned int u = (bits & 0x80000000u) ? ~bits : (bits | 0x80000000u);
            key = ((unsigned long long)u << 32) | (unsigned int)(~(unsigned int)idx);
        }
        k[i] = key;
    }
    int kk = count < K_TOP ? count : K_TOP;
    for (int j = 0; j < kk; ++j) {
        unsigned long long best = k[0];
#pragma unroll
        for (int i = 1; i < 8; ++i) if (k[i] > best) best = k[i];
#pragma unroll
        for (int off = 32; off; off >>= 1) {
            unsigned long long o = __shfl_xor(best, off);
            if (o > best) best = o;
        }
        int node = (int)(~(unsigned int)(best & 0xFFFFFFFFULL));
#pragma unroll
        for (int i = 0; i < 8; ++i) if (k[i] == best) k[i] = 0ULL;
        size_t off0 = (size_t)g * P_LEN + (size_t)j * XC;
        p[off0 + lane] = x1[(size_t)node * H1C + lane];
        if (lane == 0) p[off0 + 64] = x2[node];
    }
}

// ---------------- head ----------------
__global__ __launch_bounds__(256) void k_head(const float* __restrict__ p,
                                              const float* __restrict__ w3, const float* __restrict__ b3,
                                              const float* __restrict__ w4, const float* __restrict__ b4,
                                              const float* __restrict__ fw1, const float* __restrict__ fb1,
                                              const float* __restrict__ fw2, const float* __restrict__ fb2,
                                              float* __restrict__ out) {
    __shared__ float ps[P_LEN];
    __shared__ float h1s[C3_OUT * C3_L];
    __shared__ float h2s[C3_OUT * P2_L];
    __shared__ float h3s[FC1_IN];
    __shared__ float lls[FC1_OUT];
    __shared__ float outs[NUM_CLASSES];
    int g = blockIdx.x, tid = threadIdx.x;
    for (int i = tid; i < P_LEN; i += 256) ps[i] = p[(size_t)g * P_LEN + i];
    __syncthreads();
    for (int o = tid; o < C3_OUT * C3_L; o += 256) {
        int oc = o / C3_L, pos = o % C3_L;
        float s = b3[oc];
        const float* w = w3 + oc * C3_K;
        int base = pos * C3_K;
        for (int k = 0; k < C3_K; ++k) s += ps[base + k] * w[k];
        h1s[o] = fmaxf(s, 0.0f);
    }
    __syncthreads();
    if (tid < C3_OUT * P2_L) {
        int oc = tid / P2_L, pos = tid % P2_L;
        h2s[tid] = fmaxf(h1s[oc * C3_L + 2 * pos], h1s[oc * C3_L + 2 * pos + 1]);
    }
    __syncthreads();
    if (tid < C4_OUT * C4_L) {
        int oc = tid / C4_L, pos = tid % C4_L;
        float s = b4[oc];
        for (int ic = 0; ic < C3_OUT; ++ic)
#pragma unroll
            for (int k = 0; k < C4_K; ++k)
                s += h2s[ic * P2_L + pos + k] * w4[oc * C3_OUT * C4_K + ic * C4_K + k];
        h3s[oc * C4_L + pos] = fmaxf(s, 0.0f);
    }
    __syncthreads();
    if (tid < FC1_OUT) {
        float s = fb1[tid];
        for (int i = 0; i < FC1_IN; ++i) s += h3s[i] * fw1[i * FC1_OUT + tid];
        float v = fmaxf(s, 0.0f);
        lls[tid] = v;
        out[2 * B_GRAPHS * NUM_CLASSES + (size_t)g * FC1_OUT + tid] = v;
    }
    __syncthreads();
    if (tid < NUM_CLASSES) {
        float s = fb2[tid];
        for (int j = 0; j < FC1_OUT; ++j) s += lls[j] * fw2[j * NUM_CLASSES + tid];
        outs[tid] = s;
        out[B_GRAPHS * NUM_CLASSES + (size_t)g * NUM_CLASSES + tid] = s;
    }
    __syncthreads();
    if (tid < NUM_CLASSES) {
        float m = -INFINITY;
        for (int k2 = 0; k2 < NUM_CLASSES; ++k2) m = fmaxf(m, outs[k2]);
        float se = 0.0f;
        for (int k2 = 0; k2 < NUM_CLASSES; ++k2) se += expf(outs[k2] - m);
        out[(size_t)g * NUM_CLASSES + tid] = outs[tid] - m - logf(se);
    }
}

extern "C" void kernel_launch(void* const* d_in, const int* in_sizes, int n_in,
                              void* d_out, int out_size, void* d_ws, size_t ws_size,
                              hipStream_t stream) {
    const float* x   = (const float*)d_in[0];
    const int*   ei  = (const int*)d_in[1];
    const int*   row = ei;
    const int*   col = ei + N_EDGES;
    const int*   bat = (const int*)d_in[2];
    const float* W1  = (const float*)d_in[4];
    const float* b1  = (const float*)d_in[5];
    const float* W2  = (const float*)d_in[6];
    const float* b2  = (const float*)d_in[7];
    const float* w3  = (const float*)d_in[8];
    const float* b3  = (const float*)d_in[9];
    const float* w4  = (const float*)d_in[10];
    const float* b4  = (const float*)d_in[11];
    const float* fw1 = (const float*)d_in[12];
    const float* fb1 = (const float*)d_in[13];
    const float* fw2 = (const float*)d_in[14];
    const float* fb2 = (const float*)d_in[15];

    char* wsb = (char*)d_ws;
    unsigned short* xws = (unsigned short*)wsb;       wsb += (size_t)(N_NODES + 1) * H1C * 2; // 12.8 MB (+zero row)
    float* x1     = (float*)wsb;                      wsb += (size_t)N_NODES * H1C * 4;       // 25.6 MB
    int*   erow   = (int*)wsb;                        wsb += (size_t)NBKT * BSTRIDE * 4;      // 16.0 MB
    // ebkt aliases x1 (16.0 MB <= 25.6 MB): consumed by k_csr before k_agg1f writes x1
    unsigned int* ebkt = (unsigned int*)x1;
    int*   gcur   = (int*)wsb;                        wsb += (size_t)NBKT * 4;
    int2*  rowse  = (int2*)wsb;                       wsb += (size_t)N_NODES * 8;
    float* dis    = (float*)wsb;                      wsb += (size_t)N_NODES * 4;
    float* xws2   = (float*)wsb;                      wsb += (size_t)N_NODES * 4;
    float* x2     = (float*)wsb;                      wsb += (size_t)N_NODES * 4;
    float* p      = (float*)wsb;                      wsb += (size_t)B_GRAPHS * P_LEN * 4;
    float* outp   = (float*)d_out;

    hipMemsetAsync(gcur, 0, (size_t)NBKT * 4, stream);
    hipMemsetAsync(p, 0, (size_t)B_GRAPHS * P_LEN * 4, stream);
    hipMemsetAsync(xws + (size_t)N_NODES * H1C, 0, H1C * 2, stream);  // zero row for padding

    k_mscatter<<<(N_EDGES + MS_EPB - 1) / MS_EPB, 256, 0, stream>>>(row, col, gcur, ebkt);
    k_csr<<<NBKT, 256, 0, stream>>>(ebkt, gcur, dis, rowse, erow);
    k_xw1<<<(N_NODES + 63) / 64, 256, 0, stream>>>(x, W1, dis, xws);
    k_agg1f<<<(N_NODES + 3) / 4, 256, 0, stream>>>(rowse, erow, xws, dis, b1, W2, x1, xws2);
    k_agg2f<<<(N_NODES + 3) / 4, 256, 0, stream>>>(rowse, erow, xws2, dis, b2, x2);
    k_pool<<<(B_GRAPHS + 3) / 4, 256, 0, stream>>>(bat, x1, x2, p);
    k_head<<<B_GRAPHS, 256, 0, stream>>>(p, w3, b3, w4, b4, fw1, fb1, fw2, fb2, outp);
}